// Round 20
// baseline (2627.840 us; speedup 1.0000x reference)
//
#include <hip/hip_runtime.h>
#include <stdint.h>

#define H   300
#define HP  320
#define CAP 32     // max incoming bonds per atom (Binomial(400k,1/200k) max ~13)

using bf8 = __attribute__((ext_vector_type(8))) short;   // 8 x bf16
using s4  = __attribute__((ext_vector_type(4))) short;   // 4 x bf16 (8B store)
using f4  = __attribute__((ext_vector_type(4))) float;   // MFMA acc

__device__ __forceinline__ float bf2f(unsigned short u){
    union { unsigned int i; float f; } v; v.i = ((unsigned int)u) << 16; return v.f;
}
__device__ __forceinline__ unsigned short f2bf(float x){
    unsigned int u = __builtin_bit_cast(unsigned int, x);
    u = (u + 0x7FFFu + ((u >> 16) & 1u)) >> 16;   // RNE
    return (unsigned short)u;
}

// ---------------------------------------------------------------------------
// Incoming-bond bucket list: bucket[a][0..cnt[a]) = bond indices with dst==a
// ---------------------------------------------------------------------------
__global__ void fill_k(const int* __restrict__ b_dst, int* __restrict__ cnt,
                       int* __restrict__ bucket, int nB){
    int e = blockIdx.x * 256 + threadIdx.x;
    if (e >= nB) return;
    int d = b_dst[e];
    int slot = atomicAdd(&cnt[d], 1);
    if (slot < CAP) bucket[(long)d * CAP + slot] = e;
}

// ---------------------------------------------------------------------------
// Weight prep: W [Kact][H] fp32 -> Wt k-major [Ktot/32][320][32] bf16
// ---------------------------------------------------------------------------
__global__ void prep_wt(const float* __restrict__ W, unsigned short* __restrict__ Wt,
                        int Kact, int Kp){
    int idx = blockIdx.x * 256 + threadIdx.x;
    if (idx >= 320 * Kp) return;
    int t  = idx / (320 * 32);
    int r  = idx % (320 * 32);
    int n  = r / 32, kk = r % 32;
    int k  = t * 32 + kk;
    float v = (n < H && k < Kact) ? W[(long)k * H + n] : 0.f;
    Wt[idx] = f2bf(v);
}

// W_o [900][300] -> k-major [30][320][32]; k = t*32+kk, sec = k/320
__global__ void prep_wto(const float* __restrict__ W, unsigned short* __restrict__ Wt){
    int idx = blockIdx.x * 256 + threadIdx.x;
    if (idx >= 320 * 960) return;
    int t  = idx / (320 * 32);
    int r  = idx % (320 * 32);
    int n  = r / 32, kk = r % 32;
    int k  = t * 32 + kk;
    int sec = k / HP, ksec = k % HP;
    float v = (n < H && ksec < H) ? W[((long)sec * H + ksec) * H + n] : 0.f;
    Wt[idx] = f2bf(v);
}

// ---------------------------------------------------------------------------
// Input feature conversion: X fp32 [rows][Kact] -> Y bf16 [rows][160] linear
// ---------------------------------------------------------------------------
__global__ __launch_bounds__(256)
void conv_in(const float* __restrict__ X, int rows, int Kact,
             unsigned short* __restrict__ Y){
    int t = blockIdx.x * 256 + threadIdx.x;
    if (t >= rows * 20) return;
    int row = t / 20, c = t % 20;
    int k0 = c * 8;
    bf8 v;
    #pragma unroll
    for (int j = 0; j < 8; j++){
        int k = k0 + j;
        float f = (k < Kact) ? X[(long)row * Kact + k] : 0.f;
        v[j] = (short)f2bf(f);
    }
    *(bf8*)(Y + (long)row * 160 + k0) = v;
}

// ---------------------------------------------------------------------------
// B-stationary persistent GEMM:  out = epi( A[rows][RL] @ W^T ), BN-half=160
// EPI: 0 = relu linear, 1 = raw linear, 2 = relu + SWIZZLED store
// (chunk ^ (row&7) involution -- for buffers consumed by gemm_wo's DMA)
// ---------------------------------------------------------------------------
template<int RL, int BM, int EPI>
__global__ __launch_bounds__(256, 1)
void bstat_k(const unsigned short* __restrict__ A,    // linear [rows][RL]
             const unsigned short* __restrict__ Wt,   // k-major [T][320][32]
             unsigned short* __restrict__ outb,       // [rows][320]
             int nTiles)
{
    constexpr int T     = RL / 32;         // K-steps (5 or 10)
    constexpr int MF    = BM / 32;         // M frags per wave (1 or 2)
    constexpr int TILEB = BM * RL * 2;     // 20480 both configs

    __shared__ char ldsB[T * 10240];       // [T][4][160][16B] : 50/100 KB
    __shared__ char ldsA[2][TILEB];        // 2 x 20KB

    const int tid  = threadIdx.x;
    const int w    = tid >> 6;
    const int wm   = w >> 1, wn = w & 1;   // 2M x 2N wave grid
    const int lane = tid & 63;
    const int lr   = lane & 15;
    const int g    = lane >> 4;
    const int nh   = blockIdx.x & 1;       // N-half

    // ---- B half -> LDS, once. layout [t][g][n][16B] ----
    for (int idx = tid; idx < T * 640; idx += 256){
        int t  = idx / 640;
        int r  = idx - t * 640;
        int gg = r / 160;
        int n  = r - gg * 160;
        bf8 v = *(const bf8*)(Wt + ((long)t * 320 + nh * 160 + n) * 32 + gg * 8);
        *(bf8*)(ldsB + (long)idx * 16) = v;
    }

    auto dma = [&](int t, int buf){
        const char* g0 = (const char*)A + (long)t * TILEB + tid * 16;
        char* l0 = ldsA[buf] + (w * 64) * 16;       // wave-uniform base
        #pragma unroll
        for (int rd = 0; rd < 5; rd++)
            __builtin_amdgcn_global_load_lds(
                (const __attribute__((address_space(1))) void*)(g0 + rd * 4096),
                (__attribute__((address_space(3))) void*)(l0 + rd * 4096),
                16, 0, 0);
    };

    int tile = blockIdx.x >> 1;
    if (tile < nTiles) dma(tile, 0);
    __syncthreads();                        // B visible + prologue DMA drained

    int buf = 0;
    for (; tile < nTiles; tile += 128){
        int nt = tile + 128;
        if (nt < nTiles) dma(nt, buf ^ 1);  // lands during this K-loop

        f4 acc[MF][5];
        #pragma unroll
        for (int mf = 0; mf < MF; mf++)
            #pragma unroll
            for (int nf = 0; nf < 5; nf++)
                acc[mf][nf] = (f4){0.f, 0.f, 0.f, 0.f};

        #pragma unroll
        for (int t = 0; t < T; t++){
            bf8 bfr[5], af[MF];
            const char* bb = ldsB + (((t * 4 + g) * 160) + wn * 80 + lr) * 16;
            #pragma unroll
            for (int nf = 0; nf < 5; nf++)
                bfr[nf] = *(const bf8*)(bb + nf * 256);
            #pragma unroll
            for (int mf = 0; mf < MF; mf++){
                int row = wm * (BM / 2) + mf * 16 + lr;
                af[mf] = *(const bf8*)(ldsA[buf] + row * (RL * 2) + (t * 4 + g) * 16);
            }
            #pragma unroll
            for (int mf = 0; mf < MF; mf++)
                #pragma unroll
                for (int nf = 0; nf < 5; nf++)
                    acc[mf][nf] = __builtin_amdgcn_mfma_f32_16x16x32_bf16(
                        bfr[nf], af[mf], acc[mf][nf], 0, 0, 0);
        }

        // epilogue: D^T -> lane holds row, 4 consecutive cols
        #pragma unroll
        for (int mf = 0; mf < MF; mf++){
            const long row = (long)tile * BM + wm * (BM / 2) + mf * 16 + lr;
            #pragma unroll
            for (int nf = 0; nf < 5; nf++){
                const int colg = nh * 160 + wn * 80 + nf * 16 + g * 4;
                s4 v4;
                #pragma unroll
                for (int q = 0; q < 4; q++){
                    float v = acc[mf][nf][q];
                    if constexpr (EPI != 1) v = fmaxf(v, 0.f);
                    v4[q] = (short)f2bf(v);
                }
                if constexpr (EPI == 2){
                    int ch = colg >> 3;
                    *(s4*)(outb + row * HP + ((long)(ch ^ ((int)row & 7)) << 3)
                           + (colg & 7)) = v4;
                } else {
                    *(s4*)(outb + row * HP + colg) = v4;
                }
            }
        }
        __syncthreads();                    // DMA(next) drained + reads done
        buf ^= 1;
    }
}

// ---------------------------------------------------------------------------
// Wo GEMM: persistent, DMA-staged (no staging regs -> spill-proof),
// cross-tile double-buffered, FENCED 3-section K-loop, fused product:
//   atom_h = relu(input_atom@W0 + amsg@W1 + (input_atom*amsg)@W2 + b_o)
// input_atom/amsg stored PRE-SWIZZLED -> DMA linear, af reads XOR-swizzled
// (conflict-free). LDS 2buf x (20KB+20KB) = 80KB -> 2 blocks/CU.
// B: k-major global, 2-deep register pipeline.
// ---------------------------------------------------------------------------
__global__ __launch_bounds__(256, 2)
void gemm_wo(const unsigned short* __restrict__ A0,   // input_atom (swizzled)
             const unsigned short* __restrict__ A1,   // amsg (swizzled)
             const unsigned short* __restrict__ Wt,   // k-major [30][320][32]
             const float* __restrict__ b_o,
             unsigned short* __restrict__ outb,       // linear [rows][320]
             int nTiles)
{
    __shared__ char lds[2][2][20480];      // [buf][matrix]

    const int tid  = threadIdx.x;
    const int w    = tid >> 6;             // N stripe of 80
    const int lane = tid & 63;
    const int lr   = lane & 15;
    const int g    = lane >> 4;

    auto dma = [&](int t, int buf){
        const char* g0 = (const char*)(A0 + (long)t * 32 * HP) + tid * 16;
        const char* g1 = (const char*)(A1 + (long)t * 32 * HP) + tid * 16;
        char* l0 = lds[buf][0] + (w * 64) * 16;
        char* l1 = lds[buf][1] + (w * 64) * 16;
        #pragma unroll
        for (int rd = 0; rd < 5; rd++){
            __builtin_amdgcn_global_load_lds(
                (const __attribute__((address_space(1))) void*)(g0 + rd * 4096),
                (__attribute__((address_space(3))) void*)(l0 + rd * 4096),
                16, 0, 0);
            __builtin_amdgcn_global_load_lds(
                (const __attribute__((address_space(1))) void*)(g1 + rd * 4096),
                (__attribute__((address_space(3))) void*)(l1 + rd * 4096),
                16, 0, 0);
        }
    };

    bf8 bb[2][5];
    auto loadB = [&](int t, bf8 (&dst)[5]){
        const unsigned short* base = Wt + ((long)t * 320) * 32 + g * 8;
        #pragma unroll
        for (int n = 0; n < 5; n++)
            dst[n] = *(const bf8*)(base + (w * 80 + n * 16 + lr) * 32);
    };

    int tile = blockIdx.x;
    if (tile >= nTiles) return;
    dma(tile, 0);
    __syncthreads();                        // prologue DMA drained

    int buf = 0;
    for (; tile < nTiles; tile += (int)gridDim.x){
        int nt = tile + (int)gridDim.x;
        const bool hn = (nt < nTiles);
        if (hn) dma(nt, buf ^ 1);           // overlaps at least section 0

        f4 acc[2][5];
        #pragma unroll
        for (int m = 0; m < 2; m++)
            #pragma unroll
            for (int n = 0; n < 5; n++)
                acc[m][n] = (f4){0.f, 0.f, 0.f, 0.f};

        #pragma unroll
        for (int sec = 0; sec < 3; ++sec){
            if (sec > 0) __syncthreads();   // scheduling fence (anti-spill)
            loadB(sec * 10 + 0, bb[0]);
            loadB(sec * 10 + 1, bb[1]);

            #pragma unroll
            for (int i = 0; i < 10; i++){
                bf8 af[2];
                #pragma unroll
                for (int m = 0; m < 2; m++){
                    const int row = m * 16 + lr;
                    const int off = row * 640 + (((i * 4 + g) ^ (row & 7)) << 4);
                    if (sec == 0){
                        af[m] = *(const bf8*)(lds[buf][0] + off);
                    } else if (sec == 1){
                        af[m] = *(const bf8*)(lds[buf][1] + off);
                    } else {
                        bf8 a = *(const bf8*)(lds[buf][0] + off);
                        bf8 b = *(const bf8*)(lds[buf][1] + off);
                        #pragma unroll
                        for (int q = 0; q < 8; q++)
                            af[m][q] = (short)f2bf(bf2f((unsigned short)a[q]) *
                                                   bf2f((unsigned short)b[q]));
                    }
                }
                #pragma unroll
                for (int m = 0; m < 2; m++)
                    #pragma unroll
                    for (int n = 0; n < 5; n++)
                        acc[m][n] = __builtin_amdgcn_mfma_f32_16x16x32_bf16(
                            bb[i & 1][n], af[m], acc[m][n], 0, 0, 0);
                if (i + 2 < 10) loadB(sec * 10 + i + 2, bb[i & 1]);
            }
        }

        // epilogue: D^T -> lane holds row, 4 consecutive cols; + b_o, relu
        #pragma unroll
        for (int m = 0; m < 2; m++){
            const long row = (long)tile * 32 + m * 16 + lr;
            #pragma unroll
            for (int n = 0; n < 5; n++){
                const int colg = w * 80 + n * 16 + g * 4;
                s4 v4;
                #pragma unroll
                for (int q = 0; q < 4; q++){
                    int col = colg + q;
                    float v = acc[m][n][q];
                    v += (col < H ? b_o[col] : 0.f);
                    v4[q] = (short)f2bf(fmaxf(v, 0.f));
                }
                *(s4*)(outb + row * HP + colg) = v4;
            }
        }
        __syncthreads();                    // DMA(nt) drained + reads done
        buf ^= 1;
    }
}

// ---------------------------------------------------------------------------
// comb: msg'[e] = relu(bond_in[e] + sum_{j in bucket[src[e]]} MW[j] - MW[rev[e]])
// thread = (bond, 16B chunk); 6 independent loads in flight. Linear layout.
// ---------------------------------------------------------------------------
__global__ __launch_bounds__(256)
void comb_k(const unsigned short* __restrict__ MW,
            const unsigned short* __restrict__ bond_in,
            const int* __restrict__ b_src, const int* __restrict__ b2revb,
            const int* __restrict__ cnt, const int* __restrict__ bucket,
            unsigned short* __restrict__ out, int nB){
    int t = blockIdx.x * 256 + threadIdx.x;
    if (t >= nB * 40) return;
    int e = t / 40, ch = t % 40;
    int k0 = ch * 8;
    int s   = b_src[e];
    int rev = b2revb[e];
    int dg = cnt[s]; if (dg > CAP) dg = CAP;
    long base = (long)s * CAP;
    int be0 = 0, be1 = 0, be2 = 0, be3 = 0;
    if (dg > 0) be0 = bucket[base + 0];
    if (dg > 1) be1 = bucket[base + 1];
    if (dg > 2) be2 = bucket[base + 2];
    if (dg > 3) be3 = bucket[base + 3];
    bf8 bi = *(const bf8*)(bond_in + (long)e * HP + k0);
    bf8 rv = *(const bf8*)(MW + (long)rev * HP + k0);
    bf8 m0, m1, m2, m3;
    if (dg > 0) m0 = *(const bf8*)(MW + (long)be0 * HP + k0);
    if (dg > 1) m1 = *(const bf8*)(MW + (long)be1 * HP + k0);
    if (dg > 2) m2 = *(const bf8*)(MW + (long)be2 * HP + k0);
    if (dg > 3) m3 = *(const bf8*)(MW + (long)be3 * HP + k0);
    float sacc[8];
    #pragma unroll
    for (int q = 0; q < 8; q++)
        sacc[q] = bf2f((unsigned short)bi[q]) - bf2f((unsigned short)rv[q]);
    auto addv = [&](bf8 mm){
        #pragma unroll
        for (int q = 0; q < 8; q++) sacc[q] += bf2f((unsigned short)mm[q]);
    };
    if (dg > 0) addv(m0);
    if (dg > 1) addv(m1);
    if (dg > 2) addv(m2);
    if (dg > 3) addv(m3);
    for (int j = 4; j < dg; ++j){
        int be = bucket[base + j];
        addv(*(const bf8*)(MW + (long)be * HP + k0));
    }
    bf8 v;
    #pragma unroll
    for (int q = 0; q < 8; q++) v[q] = (short)f2bf(fmaxf(sacc[q], 0.f));
    *(bf8*)(out + (long)e * HP + k0) = v;
}

// ---------------------------------------------------------------------------
// a_msg[a] = sum of msg rows with dst==a -> SWIZZLED store (gemm_wo input)
// ---------------------------------------------------------------------------
__global__ __launch_bounds__(256)
void amsg_k(const unsigned short* __restrict__ msg, const int* __restrict__ cnt,
            const int* __restrict__ bucket,
            unsigned short* __restrict__ amsg, int nA){
    int t = blockIdx.x * 256 + threadIdx.x;
    if (t >= nA * 40) return;
    int a = t / 40, ch = t % 40;
    int k0 = ch * 8;
    int dg = cnt[a]; if (dg > CAP) dg = CAP;
    long base = (long)a * CAP;
    int be0 = 0, be1 = 0, be2 = 0, be3 = 0;
    if (dg > 0) be0 = bucket[base + 0];
    if (dg > 1) be1 = bucket[base + 1];
    if (dg > 2) be2 = bucket[base + 2];
    if (dg > 3) be3 = bucket[base + 3];
    bf8 m0, m1, m2, m3;
    if (dg > 0) m0 = *(const bf8*)(msg + (long)be0 * HP + k0);
    if (dg > 1) m1 = *(const bf8*)(msg + (long)be1 * HP + k0);
    if (dg > 2) m2 = *(const bf8*)(msg + (long)be2 * HP + k0);
    if (dg > 3) m3 = *(const bf8*)(msg + (long)be3 * HP + k0);
    float s[8];
    #pragma unroll
    for (int q = 0; q < 8; q++) s[q] = 0.f;
    auto addv = [&](bf8 mm){
        #pragma unroll
        for (int q = 0; q < 8; q++) s[q] += bf2f((unsigned short)mm[q]);
    };
    if (dg > 0) addv(m0);
    if (dg > 1) addv(m1);
    if (dg > 2) addv(m2);
    if (dg > 3) addv(m3);
    for (int j = 4; j < dg; ++j)
        addv(*(const bf8*)(msg + (long)bucket[base + j] * HP + k0));
    bf8 va;
    #pragma unroll
    for (int q = 0; q < 8; q++) va[q] = (short)f2bf(s[q]);
    *(bf8*)(amsg + (long)a * HP + ((long)(ch ^ (a & 7)) << 3)) = va;
}

// ---------------------------------------------------------------------------
// Readout: per-molecule mean over sorted mol_ids (binary-search range)
// ---------------------------------------------------------------------------
__global__ __launch_bounds__(320)
void readout_k(const unsigned short* __restrict__ atom_h,
               const int* __restrict__ mol_ids, int nAtoms,
               float* __restrict__ out){
    int m = blockIdx.x;
    int t = threadIdx.x;
    int lo = 0, hi = nAtoms;
    while (lo < hi){ int mid = (lo + hi) >> 1; if (mol_ids[mid] < m) lo = mid + 1; else hi = mid; }
    int lo2 = lo, hi2 = nAtoms;
    while (lo2 < hi2){ int mid = (lo2 + hi2) >> 1; if (mol_ids[mid] < m + 1) lo2 = mid + 1; else hi2 = mid; }
    if (t < H){
        float s = 0.f;
        for (int a = lo; a < lo2; ++a) s += bf2f(atom_h[(long)a * HP + t]);
        int c2 = lo2 - lo;
        out[(long)m * H + t] = s / (float)(c2 > 0 ? c2 : 1);
    }
}

// ---------------------------------------------------------------------------
extern "C" void kernel_launch(void* const* d_in, const int* in_sizes, int n_in,
                              void* d_out, int out_size, void* d_ws, size_t ws_size,
                              hipStream_t stream){
    const float* f_atoms  = (const float*)d_in[0];
    const float* f_bonds  = (const float*)d_in[1];
    const float* W_i_atom = (const float*)d_in[2];
    const float* W_i_bond = (const float*)d_in[3];
    const float* W_h      = (const float*)d_in[4];
    const float* W_o      = (const float*)d_in[5];
    const float* b_o      = (const float*)d_in[6];
    const int* b_src   = (const int*)d_in[7];
    const int* b_dst   = (const int*)d_in[8];
    const int* b2revb  = (const int*)d_in[9];
    const int* mol_ids = (const int*)d_in[10];

    const int nA = in_sizes[10];          // 200000
    const int nB = in_sizes[7];           // 400000
    const int nM = out_size / H;          // 4096

    char* p = (char*)d_ws;
    auto alloc = [&](size_t bytes){ char* q = p; p += (bytes + 255) & ~(size_t)255; return q; };
    unsigned short* Wt_ia = (unsigned short*)alloc((size_t)320 * 160 * 2);
    unsigned short* Wt_ib = (unsigned short*)alloc((size_t)320 * 160 * 2);
    unsigned short* Wt_h  = (unsigned short*)alloc((size_t)3 * 320 * 320 * 2);
    unsigned short* Wt_o  = (unsigned short*)alloc((size_t)320 * 960 * 2);
    int* cnt    = (int*)alloc((size_t)nA * 4);
    int* bucket = (int*)alloc((size_t)nA * CAP * 4);
    unsigned short* input_atom = (unsigned short*)alloc((size_t)nA * HP * 2);
    unsigned short* input_bond = (unsigned short*)alloc((size_t)nB * HP * 2);
    unsigned short* msgA = (unsigned short*)alloc((size_t)nB * HP * 2);
    unsigned short* MW   = (unsigned short*)alloc((size_t)nB * HP * 2);
    // aliases into dead regions:
    unsigned short* fa_bf  = MW;                                  // [nA][160]
    unsigned short* fb_bf  = MW + (size_t)nA * 160;               // [nB][160]
    unsigned short* amsg   = MW;                                  // MW dead after comb3
    unsigned short* atom_h = input_bond;                          // dead after comb3

    if ((size_t)(p - (char*)d_ws) > ws_size) return;  // diagnostic: ws too small

    // adjacency buckets
    hipMemsetAsync(cnt, 0, (size_t)nA * 4, stream);
    fill_k<<<dim3((nB + 255) / 256), dim3(256), 0, stream>>>(b_dst, cnt, bucket, nB);

    // weight prep (k-major) + input conversion (linear)
    prep_wt<<<dim3((320*160 + 255)/256), dim3(256), 0, stream>>>(W_i_atom, Wt_ia, 133, 160);
    prep_wt<<<dim3((320*160 + 255)/256), dim3(256), 0, stream>>>(W_i_bond, Wt_ib, 147, 160);
    for (int d = 0; d < 3; d++)
        prep_wt<<<dim3((320*320 + 255)/256), dim3(256), 0, stream>>>(
            W_h + (size_t)d * H * H, Wt_h + (size_t)d * 320 * 320, 300, 320);
    prep_wto<<<dim3((320*960 + 255)/256), dim3(256), 0, stream>>>(W_o, Wt_o);
    conv_in<<<dim3((nA*20 + 255)/256), dim3(256), 0, stream>>>(f_atoms, nA, 133, fa_bf);
    conv_in<<<dim3((nB*20 + 255)/256), dim3(256), 0, stream>>>(f_bonds, nB, 147, fb_bf);

    // input projections (B-stationary, RL=160, BM=64)
    // input_atom stored SWIZZLED (only consumer: gemm_wo DMA)
    bstat_k<160,64,2><<<dim3(256), dim3(256), 0, stream>>>(
        fa_bf, Wt_ia, input_atom, nA / 64);
    bstat_k<160,64,0><<<dim3(256), dim3(256), 0, stream>>>(
        fb_bf, Wt_ib, input_bond, nB / 64);

    // message steps: MW = msg @ W_h[d]; msg' = relu(bond_in + bucket-sum - rev)
    const int combGrid = (nB * 40 + 255) / 256;
    const unsigned short* msg_cur = input_bond;
    for (int d = 0; d < 3; d++){
        bstat_k<320,32,1><<<dim3(256), dim3(256), 0, stream>>>(
            msg_cur, Wt_h + (size_t)d * 320 * 320, MW, nB / 32);
        comb_k<<<dim3(combGrid), dim3(256), 0, stream>>>(
            MW, input_bond, b_src, b2revb, cnt, bucket, msgA, nB);
        msg_cur = msgA;
    }

    // final per-atom aggregation (SWIZZLED output for gemm_wo DMA)
    amsg_k<<<dim3((nA * 40 + 255) / 256), dim3(256), 0, stream>>>(
        msgA, cnt, bucket, amsg, nA);

    // atom_h = relu([input_atom | amsg | input_atom*amsg] @ W_o + b_o)
    // persistent DMA double-buffered, fenced sections, fused product
    gemm_wo<<<dim3(512), dim3(256), 0, stream>>>(
        input_atom, amsg, Wt_o, b_o, atom_h, nA / 32);

    // per-molecule mean
    readout_k<<<dim3(nM), dim3(320), 0, stream>>>(atom_h, mol_ids, nA, (float*)d_out);
}

// Round 21
// 2135.036 us; speedup vs baseline: 1.2308x; 1.2308x over previous
//
#include <hip/hip_runtime.h>
#include <stdint.h>

#define H   300
#define HP  320
#define CAP 32     // max incoming bonds per atom (Binomial(400k,1/200k) max ~13)

using bf8 = __attribute__((ext_vector_type(8))) short;   // 8 x bf16
using s4  = __attribute__((ext_vector_type(4))) short;   // 4 x bf16 (8B store)
using f4  = __attribute__((ext_vector_type(4))) float;   // MFMA acc

__device__ __forceinline__ float bf2f(unsigned short u){
    union { unsigned int i; float f; } v; v.i = ((unsigned int)u) << 16; return v.f;
}
__device__ __forceinline__ unsigned short f2bf(float x){
    unsigned int u = __builtin_bit_cast(unsigned int, x);
    u = (u + 0x7FFFu + ((u >> 16) & 1u)) >> 16;   // RNE
    return (unsigned short)u;
}

// ---------------------------------------------------------------------------
// Incoming-bond bucket list: bucket[a][0..cnt[a]) = bond indices with dst==a
// ---------------------------------------------------------------------------
__global__ void fill_k(const int* __restrict__ b_dst, int* __restrict__ cnt,
                       int* __restrict__ bucket, int nB){
    int e = blockIdx.x * 256 + threadIdx.x;
    if (e >= nB) return;
    int d = b_dst[e];
    int slot = atomicAdd(&cnt[d], 1);
    if (slot < CAP) bucket[(long)d * CAP + slot] = e;
}

// ---------------------------------------------------------------------------
// Weight prep: W [Kact][H] fp32 -> Wt k-major [Ktot/32][320][32] bf16
// ---------------------------------------------------------------------------
__global__ void prep_wt(const float* __restrict__ W, unsigned short* __restrict__ Wt,
                        int Kact, int Kp){
    int idx = blockIdx.x * 256 + threadIdx.x;
    if (idx >= 320 * Kp) return;
    int t  = idx / (320 * 32);
    int r  = idx % (320 * 32);
    int n  = r / 32, kk = r % 32;
    int k  = t * 32 + kk;
    float v = (n < H && k < Kact) ? W[(long)k * H + n] : 0.f;
    Wt[idx] = f2bf(v);
}

// W_o [900][300] -> k-major [30][320][32]; k = t*32+kk, sec = k/320
__global__ void prep_wto(const float* __restrict__ W, unsigned short* __restrict__ Wt){
    int idx = blockIdx.x * 256 + threadIdx.x;
    if (idx >= 320 * 960) return;
    int t  = idx / (320 * 32);
    int r  = idx % (320 * 32);
    int n  = r / 32, kk = r % 32;
    int k  = t * 32 + kk;
    int sec = k / HP, ksec = k % HP;
    float v = (n < H && ksec < H) ? W[((long)sec * H + ksec) * H + n] : 0.f;
    Wt[idx] = f2bf(v);
}

// ---------------------------------------------------------------------------
// Input feature conversion: X fp32 [rows][Kact] -> Y bf16 [rows][160] linear
// ---------------------------------------------------------------------------
__global__ __launch_bounds__(256)
void conv_in(const float* __restrict__ X, int rows, int Kact,
             unsigned short* __restrict__ Y){
    int t = blockIdx.x * 256 + threadIdx.x;
    if (t >= rows * 20) return;
    int row = t / 20, c = t % 20;
    int k0 = c * 8;
    bf8 v;
    #pragma unroll
    for (int j = 0; j < 8; j++){
        int k = k0 + j;
        float f = (k < Kact) ? X[(long)row * Kact + k] : 0.f;
        v[j] = (short)f2bf(f);
    }
    *(bf8*)(Y + (long)row * 160 + k0) = v;
}

// ---------------------------------------------------------------------------
// B-stationary persistent GEMM:  out = epi( A[rows][RL] @ W^T ), BN-half=160
// grid = 256 (1 block/CU). Block owns N-half; B-half (RL x 160, k-major)
// lives in LDS for the whole kernel -> K-loop has ZERO global loads.
// A tiles (BM x RL = 20KB LINEAR row-major = contiguous) streamed via
// global_load_lds DMA, double-buffered. No staging registers -> no spill.
// EPI: 0 = relu, 1 = raw.
// ---------------------------------------------------------------------------
template<int RL, int BM, int EPI>
__global__ __launch_bounds__(256, 1)
void bstat_k(const unsigned short* __restrict__ A,    // linear [rows][RL]
             const unsigned short* __restrict__ Wt,   // k-major [T][320][32]
             unsigned short* __restrict__ outb,       // linear [rows][320]
             int nTiles)
{
    constexpr int T     = RL / 32;         // K-steps (5 or 10)
    constexpr int MF    = BM / 32;         // M frags per wave (1 or 2)
    constexpr int TILEB = BM * RL * 2;     // 20480 both configs

    __shared__ char ldsB[T * 10240];       // [T][4][160][16B] : 50/100 KB
    __shared__ char ldsA[2][TILEB];        // 2 x 20KB

    const int tid  = threadIdx.x;
    const int w    = tid >> 6;
    const int wm   = w >> 1, wn = w & 1;   // 2M x 2N wave grid
    const int lane = tid & 63;
    const int lr   = lane & 15;
    const int g    = lane >> 4;
    const int nh   = blockIdx.x & 1;       // N-half

    // ---- B half -> LDS, once. layout [t][g][n][16B] ----
    for (int idx = tid; idx < T * 640; idx += 256){
        int t  = idx / 640;
        int r  = idx - t * 640;
        int gg = r / 160;
        int n  = r - gg * 160;
        bf8 v = *(const bf8*)(Wt + ((long)t * 320 + nh * 160 + n) * 32 + gg * 8);
        *(bf8*)(ldsB + (long)idx * 16) = v;
    }

    auto dma = [&](int t, int buf){
        const char* g0 = (const char*)A + (long)t * TILEB + tid * 16;
        char* l0 = ldsA[buf] + (w * 64) * 16;       // wave-uniform base
        #pragma unroll
        for (int rd = 0; rd < 5; rd++)
            __builtin_amdgcn_global_load_lds(
                (const __attribute__((address_space(1))) void*)(g0 + rd * 4096),
                (__attribute__((address_space(3))) void*)(l0 + rd * 4096),
                16, 0, 0);
    };

    int tile = blockIdx.x >> 1;
    if (tile < nTiles) dma(tile, 0);
    __syncthreads();                        // B visible + prologue DMA drained

    int buf = 0;
    for (; tile < nTiles; tile += 128){
        int nt = tile + 128;
        if (nt < nTiles) dma(nt, buf ^ 1);  // lands during this K-loop

        f4 acc[MF][5];
        #pragma unroll
        for (int mf = 0; mf < MF; mf++)
            #pragma unroll
            for (int nf = 0; nf < 5; nf++)
                acc[mf][nf] = (f4){0.f, 0.f, 0.f, 0.f};

        #pragma unroll
        for (int t = 0; t < T; t++){
            bf8 bfr[5], af[MF];
            const char* bb = ldsB + (((t * 4 + g) * 160) + wn * 80 + lr) * 16;
            #pragma unroll
            for (int nf = 0; nf < 5; nf++)
                bfr[nf] = *(const bf8*)(bb + nf * 256);
            #pragma unroll
            for (int mf = 0; mf < MF; mf++){
                int row = wm * (BM / 2) + mf * 16 + lr;
                af[mf] = *(const bf8*)(ldsA[buf] + row * (RL * 2) + (t * 4 + g) * 16);
            }
            #pragma unroll
            for (int mf = 0; mf < MF; mf++)
                #pragma unroll
                for (int nf = 0; nf < 5; nf++)
                    acc[mf][nf] = __builtin_amdgcn_mfma_f32_16x16x32_bf16(
                        bfr[nf], af[mf], acc[mf][nf], 0, 0, 0);
        }

        // epilogue: D^T -> lane holds row, 4 consecutive cols
        #pragma unroll
        for (int mf = 0; mf < MF; mf++){
            const long row = (long)tile * BM + wm * (BM / 2) + mf * 16 + lr;
            #pragma unroll
            for (int nf = 0; nf < 5; nf++){
                const int colg = nh * 160 + wn * 80 + nf * 16 + g * 4;
                s4 v4;
                #pragma unroll
                for (int q = 0; q < 4; q++){
                    float v = acc[mf][nf][q];
                    if constexpr (EPI == 0) v = fmaxf(v, 0.f);
                    v4[q] = (short)f2bf(v);
                }
                *(s4*)(outb + row * HP + colg) = v4;
            }
        }
        __syncthreads();                    // DMA(next) drained + reads done
        buf ^= 1;
    }
}

// ---------------------------------------------------------------------------
// Wo GEMM, fused product, SECTION-FENCED (anti-spill, r19-proven):
//   atom_h = relu(input_atom@W0 + amsg@W1 + (input_atom*amsg)@W2 + b_o)
// Stage both 32x320 tiles via TRANSIENT regs into XOR-swizzled lds0/lds1;
// ONE barrier; then THREE separate 10-step K-loops with __syncthreads()
// fences between (stops cross-section pipelining/spill). sec2 af =
// lds0*lds1 in-register. B: k-major global, 2-deep register pipeline.
// ---------------------------------------------------------------------------
__global__ __launch_bounds__(256, 4)
void gemm_wo(const unsigned short* __restrict__ A0,   // input_atom [rows][320]
             const unsigned short* __restrict__ A1,   // amsg       [rows][320]
             const unsigned short* __restrict__ Wt,   // k-major [30][320][32]
             const float* __restrict__ b_o,
             unsigned short* __restrict__ outb,       // linear [rows][320]
             int nTiles)
{
    __shared__ char lds0[32 * 640];        // XOR-swizzled
    __shared__ char lds1[32 * 640];

    const int tid  = threadIdx.x;
    const int w    = tid >> 6;             // N stripe of 80
    const int lane = tid & 63;
    const int lr   = lane & 15;
    const int g    = lane >> 4;

    int tile = blockIdx.x;
    if (tile >= nTiles) return;
    const long rowBase = (long)tile * 32;

    auto stageA = [&](const unsigned short* src, char* dst){
        const char* gb = (const char*)(src + rowBase * HP);
        bf8 st[5];                          // transient: dead before K-loop
        #pragma unroll
        for (int i = 0; i < 5; i++)
            st[i] = *(const bf8*)(gb + (i * 256 + tid) * 16);
        #pragma unroll
        for (int i = 0; i < 5; i++){
            int f = i * 256 + tid;
            int row = f / 40, c = f % 40;
            *(bf8*)(dst + row * 640 + ((c ^ (row & 7)) << 4)) = st[i];
        }
    };

    bf8 bb[2][5];
    auto loadB = [&](int t, bf8 (&dst)[5]){
        const unsigned short* base = Wt + ((long)t * 320) * 32 + g * 8;
        #pragma unroll
        for (int n = 0; n < 5; n++)
            dst[n] = *(const bf8*)(base + (w * 80 + n * 16 + lr) * 32);
    };

    stageA(A0, lds0);
    stageA(A1, lds1);
    loadB(0, bb[0]);                        // latency hides under stage drain
    __syncthreads();                        // LDS read-only after this

    f4 acc[2][5];
    #pragma unroll
    for (int m = 0; m < 2; m++)
        #pragma unroll
        for (int n = 0; n < 5; n++)
            acc[m][n] = (f4){0.f, 0.f, 0.f, 0.f};

    #pragma unroll
    for (int sec = 0; sec < 3; ++sec){
        if (sec > 0){
            __syncthreads();               // scheduling fence (anti-spill)
            loadB(sec * 10, bb[0]);
        }
        loadB(sec * 10 + 1, bb[1]);

        #pragma unroll
        for (int i = 0; i < 10; i++){
            bf8 af[2];
            #pragma unroll
            for (int m = 0; m < 2; m++){
                const int row = m * 16 + lr;
                const int off = row * 640 + (((i * 4 + g) ^ (row & 7)) << 4);
                if (sec == 0){
                    af[m] = *(const bf8*)(lds0 + off);
                } else if (sec == 1){
                    af[m] = *(const bf8*)(lds1 + off);
                } else {
                    bf8 a = *(const bf8*)(lds0 + off);
                    bf8 b = *(const bf8*)(lds1 + off);
                    #pragma unroll
                    for (int q = 0; q < 8; q++)
                        af[m][q] = (short)f2bf(bf2f((unsigned short)a[q]) *
                                               bf2f((unsigned short)b[q]));
                }
            }
            #pragma unroll
            for (int m = 0; m < 2; m++)
                #pragma unroll
                for (int n = 0; n < 5; n++)
                    acc[m][n] = __builtin_amdgcn_mfma_f32_16x16x32_bf16(
                        bb[i & 1][n], af[m], acc[m][n], 0, 0, 0);
            if (i + 2 < 10) loadB(sec * 10 + i + 2, bb[i & 1]);
        }
    }

    // epilogue: D^T -> lane holds row, 4 consecutive cols; + b_o, relu
    #pragma unroll
    for (int m = 0; m < 2; m++){
        const long row = rowBase + m * 16 + lr;
        #pragma unroll
        for (int n = 0; n < 5; n++){
            const int colg = w * 80 + n * 16 + g * 4;
            s4 v4;
            #pragma unroll
            for (int q = 0; q < 4; q++){
                int col = colg + q;
                float v = acc[m][n][q];
                v += (col < H ? b_o[col] : 0.f);
                v4[q] = (short)f2bf(fmaxf(v, 0.f));
            }
            *(s4*)(outb + row * HP + colg) = v4;
        }
    }
}

// ---------------------------------------------------------------------------
// comb: msg'[e] = relu(bond_in[e] + sum_{j in bucket[src[e]]} MW[j] - MW[rev[e]])
// thread = (bond, 16B chunk); 6 independent loads in flight. Linear layout.
// ---------------------------------------------------------------------------
__global__ __launch_bounds__(256)
void comb_k(const unsigned short* __restrict__ MW,
            const unsigned short* __restrict__ bond_in,
            const int* __restrict__ b_src, const int* __restrict__ b2revb,
            const int* __restrict__ cnt, const int* __restrict__ bucket,
            unsigned short* __restrict__ out, int nB){
    int t = blockIdx.x * 256 + threadIdx.x;
    if (t >= nB * 40) return;
    int e = t / 40, ch = t % 40;
    int k0 = ch * 8;
    int s   = b_src[e];
    int rev = b2revb[e];
    int dg = cnt[s]; if (dg > CAP) dg = CAP;
    long base = (long)s * CAP;
    int be0 = 0, be1 = 0, be2 = 0, be3 = 0;
    if (dg > 0) be0 = bucket[base + 0];
    if (dg > 1) be1 = bucket[base + 1];
    if (dg > 2) be2 = bucket[base + 2];
    if (dg > 3) be3 = bucket[base + 3];
    bf8 bi = *(const bf8*)(bond_in + (long)e * HP + k0);
    bf8 rv = *(const bf8*)(MW + (long)rev * HP + k0);
    bf8 m0, m1, m2, m3;
    if (dg > 0) m0 = *(const bf8*)(MW + (long)be0 * HP + k0);
    if (dg > 1) m1 = *(const bf8*)(MW + (long)be1 * HP + k0);
    if (dg > 2) m2 = *(const bf8*)(MW + (long)be2 * HP + k0);
    if (dg > 3) m3 = *(const bf8*)(MW + (long)be3 * HP + k0);
    float sacc[8];
    #pragma unroll
    for (int q = 0; q < 8; q++)
        sacc[q] = bf2f((unsigned short)bi[q]) - bf2f((unsigned short)rv[q]);
    auto addv = [&](bf8 mm){
        #pragma unroll
        for (int q = 0; q < 8; q++) sacc[q] += bf2f((unsigned short)mm[q]);
    };
    if (dg > 0) addv(m0);
    if (dg > 1) addv(m1);
    if (dg > 2) addv(m2);
    if (dg > 3) addv(m3);
    for (int j = 4; j < dg; ++j){
        int be = bucket[base + j];
        addv(*(const bf8*)(MW + (long)be * HP + k0));
    }
    bf8 v;
    #pragma unroll
    for (int q = 0; q < 8; q++) v[q] = (short)f2bf(fmaxf(sacc[q], 0.f));
    *(bf8*)(out + (long)e * HP + k0) = v;
}

// ---------------------------------------------------------------------------
// a_msg[a] = sum of msg rows with dst==a (bf16, linear)
// ---------------------------------------------------------------------------
__global__ __launch_bounds__(256)
void amsg_k(const unsigned short* __restrict__ msg, const int* __restrict__ cnt,
            const int* __restrict__ bucket,
            unsigned short* __restrict__ amsg, int nA){
    int t = blockIdx.x * 256 + threadIdx.x;
    if (t >= nA * 40) return;
    int a = t / 40, ch = t % 40;
    int k0 = ch * 8;
    int dg = cnt[a]; if (dg > CAP) dg = CAP;
    long base = (long)a * CAP;
    int be0 = 0, be1 = 0, be2 = 0, be3 = 0;
    if (dg > 0) be0 = bucket[base + 0];
    if (dg > 1) be1 = bucket[base + 1];
    if (dg > 2) be2 = bucket[base + 2];
    if (dg > 3) be3 = bucket[base + 3];
    bf8 m0, m1, m2, m3;
    if (dg > 0) m0 = *(const bf8*)(msg + (long)be0 * HP + k0);
    if (dg > 1) m1 = *(const bf8*)(msg + (long)be1 * HP + k0);
    if (dg > 2) m2 = *(const bf8*)(msg + (long)be2 * HP + k0);
    if (dg > 3) m3 = *(const bf8*)(msg + (long)be3 * HP + k0);
    float s[8];
    #pragma unroll
    for (int q = 0; q < 8; q++) s[q] = 0.f;
    auto addv = [&](bf8 mm){
        #pragma unroll
        for (int q = 0; q < 8; q++) s[q] += bf2f((unsigned short)mm[q]);
    };
    if (dg > 0) addv(m0);
    if (dg > 1) addv(m1);
    if (dg > 2) addv(m2);
    if (dg > 3) addv(m3);
    for (int j = 4; j < dg; ++j)
        addv(*(const bf8*)(msg + (long)bucket[base + j] * HP + k0));
    bf8 va;
    #pragma unroll
    for (int q = 0; q < 8; q++) va[q] = (short)f2bf(s[q]);
    *(bf8*)(amsg + (long)a * HP + k0) = va;
}

// ---------------------------------------------------------------------------
// Readout: per-molecule mean over sorted mol_ids (binary-search range)
// ---------------------------------------------------------------------------
__global__ __launch_bounds__(320)
void readout_k(const unsigned short* __restrict__ atom_h,
               const int* __restrict__ mol_ids, int nAtoms,
               float* __restrict__ out){
    int m = blockIdx.x;
    int t = threadIdx.x;
    int lo = 0, hi = nAtoms;
    while (lo < hi){ int mid = (lo + hi) >> 1; if (mol_ids[mid] < m) lo = mid + 1; else hi = mid; }
    int lo2 = lo, hi2 = nAtoms;
    while (lo2 < hi2){ int mid = (lo2 + hi2) >> 1; if (mol_ids[mid] < m + 1) lo2 = mid + 1; else hi2 = mid; }
    if (t < H){
        float s = 0.f;
        for (int a = lo; a < lo2; ++a) s += bf2f(atom_h[(long)a * HP + t]);
        int c2 = lo2 - lo;
        out[(long)m * H + t] = s / (float)(c2 > 0 ? c2 : 1);
    }
}

// ---------------------------------------------------------------------------
extern "C" void kernel_launch(void* const* d_in, const int* in_sizes, int n_in,
                              void* d_out, int out_size, void* d_ws, size_t ws_size,
                              hipStream_t stream){
    const float* f_atoms  = (const float*)d_in[0];
    const float* f_bonds  = (const float*)d_in[1];
    const float* W_i_atom = (const float*)d_in[2];
    const float* W_i_bond = (const float*)d_in[3];
    const float* W_h      = (const float*)d_in[4];
    const float* W_o      = (const float*)d_in[5];
    const float* b_o      = (const float*)d_in[6];
    const int* b_src   = (const int*)d_in[7];
    const int* b_dst   = (const int*)d_in[8];
    const int* b2revb  = (const int*)d_in[9];
    const int* mol_ids = (const int*)d_in[10];

    const int nA = in_sizes[10];          // 200000
    const int nB = in_sizes[7];           // 400000
    const int nM = out_size / H;          // 4096

    char* p = (char*)d_ws;
    auto alloc = [&](size_t bytes){ char* q = p; p += (bytes + 255) & ~(size_t)255; return q; };
    unsigned short* Wt_ia = (unsigned short*)alloc((size_t)320 * 160 * 2);
    unsigned short* Wt_ib = (unsigned short*)alloc((size_t)320 * 160 * 2);
    unsigned short* Wt_h  = (unsigned short*)alloc((size_t)3 * 320 * 320 * 2);
    unsigned short* Wt_o  = (unsigned short*)alloc((size_t)320 * 960 * 2);
    int* cnt    = (int*)alloc((size_t)nA * 4);
    int* bucket = (int*)alloc((size_t)nA * CAP * 4);
    unsigned short* input_atom = (unsigned short*)alloc((size_t)nA * HP * 2);
    unsigned short* input_bond = (unsigned short*)alloc((size_t)nB * HP * 2);
    unsigned short* msgA = (unsigned short*)alloc((size_t)nB * HP * 2);
    unsigned short* MW   = (unsigned short*)alloc((size_t)nB * HP * 2);
    // aliases into dead regions:
    unsigned short* fa_bf  = MW;                                  // [nA][160]
    unsigned short* fb_bf  = MW + (size_t)nA * 160;               // [nB][160]
    unsigned short* amsg   = MW;                                  // MW dead after comb3
    unsigned short* atom_h = input_bond;                          // dead after comb3

    if ((size_t)(p - (char*)d_ws) > ws_size) return;  // diagnostic: ws too small

    // adjacency buckets
    hipMemsetAsync(cnt, 0, (size_t)nA * 4, stream);
    fill_k<<<dim3((nB + 255) / 256), dim3(256), 0, stream>>>(b_dst, cnt, bucket, nB);

    // weight prep (k-major) + input conversion (linear)
    prep_wt<<<dim3((320*160 + 255)/256), dim3(256), 0, stream>>>(W_i_atom, Wt_ia, 133, 160);
    prep_wt<<<dim3((320*160 + 255)/256), dim3(256), 0, stream>>>(W_i_bond, Wt_ib, 147, 160);
    for (int d = 0; d < 3; d++)
        prep_wt<<<dim3((320*320 + 255)/256), dim3(256), 0, stream>>>(
            W_h + (size_t)d * H * H, Wt_h + (size_t)d * 320 * 320, 300, 320);
    prep_wto<<<dim3((320*960 + 255)/256), dim3(256), 0, stream>>>(W_o, Wt_o);
    conv_in<<<dim3((nA*20 + 255)/256), dim3(256), 0, stream>>>(f_atoms, nA, 133, fa_bf);
    conv_in<<<dim3((nB*20 + 255)/256), dim3(256), 0, stream>>>(f_bonds, nB, 147, fb_bf);

    // input projections (B-stationary, RL=160, BM=64)
    bstat_k<160,64,0><<<dim3(256), dim3(256), 0, stream>>>(
        fa_bf, Wt_ia, input_atom, nA / 64);
    bstat_k<160,64,0><<<dim3(256), dim3(256), 0, stream>>>(
        fb_bf, Wt_ib, input_bond, nB / 64);

    // message steps: MW = msg @ W_h[d]; msg' = relu(bond_in + bucket-sum - rev)
    const int combGrid = (nB * 40 + 255) / 256;
    const unsigned short* msg_cur = input_bond;
    for (int d = 0; d < 3; d++){
        bstat_k<320,32,1><<<dim3(256), dim3(256), 0, stream>>>(
            msg_cur, Wt_h + (size_t)d * 320 * 320, MW, nB / 32);
        comb_k<<<dim3(combGrid), dim3(256), 0, stream>>>(
            MW, input_bond, b_src, b2revb, cnt, bucket, msgA, nB);
        msg_cur = msgA;
    }

    // final per-atom aggregation (linear, no prod materialization)
    amsg_k<<<dim3((nA * 40 + 255) / 256), dim3(256), 0, stream>>>(
        msgA, cnt, bucket, amsg, nA);

    // atom_h = relu([input_atom | amsg | input_atom*amsg] @ W_o + b_o)
    // product fused in-kernel; three fenced 10-step sections (anti-spill)
    gemm_wo<<<dim3(nA / 32), dim3(256), 0, stream>>>(
        input_atom, amsg, Wt_o, b_o, atom_h, nA / 32);

    // per-molecule mean
    readout_k<<<dim3(nM), dim3(320), 0, stream>>>(atom_h, mol_ids, nA, (float*)d_out);
}

// Round 22
// 1964.666 us; speedup vs baseline: 1.3376x; 1.0867x over previous
//
#include <hip/hip_runtime.h>
#include <stdint.h>

#define H   300
#define HP  320
#define CAP 32     // max incoming bonds per atom (Binomial(400k,1/200k) max ~13)

using bf8 = __attribute__((ext_vector_type(8))) short;   // 8 x bf16
using s4  = __attribute__((ext_vector_type(4))) short;   // 4 x bf16 (8B store)
using f4  = __attribute__((ext_vector_type(4))) float;   // MFMA acc

__device__ __forceinline__ float bf2f(unsigned short u){
    union { unsigned int i; float f; } v; v.i = ((unsigned int)u) << 16; return v.f;
}
__device__ __forceinline__ unsigned short f2bf(float x){
    unsigned int u = __builtin_bit_cast(unsigned int, x);
    u = (u + 0x7FFFu + ((u >> 16) & 1u)) >> 16;   // RNE
    return (unsigned short)u;
}

// ---------------------------------------------------------------------------
// Incoming-bond bucket list: bucket[a][0..cnt[a]) = bond indices with dst==a
// ---------------------------------------------------------------------------
__global__ void fill_k(const int* __restrict__ b_dst, int* __restrict__ cnt,
                       int* __restrict__ bucket, int nB){
    int e = blockIdx.x * 256 + threadIdx.x;
    if (e >= nB) return;
    int d = b_dst[e];
    int slot = atomicAdd(&cnt[d], 1);
    if (slot < CAP) bucket[(long)d * CAP + slot] = e;
}

// ---------------------------------------------------------------------------
// Weight prep: W [Kact][H] fp32 -> Wt k-major [Ktot/32][320][32] bf16
// ---------------------------------------------------------------------------
__global__ void prep_wt(const float* __restrict__ W, unsigned short* __restrict__ Wt,
                        int Kact, int Kp){
    int idx = blockIdx.x * 256 + threadIdx.x;
    if (idx >= 320 * Kp) return;
    int t  = idx / (320 * 32);
    int r  = idx % (320 * 32);
    int n  = r / 32, kk = r % 32;
    int k  = t * 32 + kk;
    float v = (n < H && k < Kact) ? W[(long)k * H + n] : 0.f;
    Wt[idx] = f2bf(v);
}

// W_o [900][300] -> k-major [30][320][32]; k = t*32+kk, sec = k/320
__global__ void prep_wto(const float* __restrict__ W, unsigned short* __restrict__ Wt){
    int idx = blockIdx.x * 256 + threadIdx.x;
    if (idx >= 320 * 960) return;
    int t  = idx / (320 * 32);
    int r  = idx % (320 * 32);
    int n  = r / 32, kk = r % 32;
    int k  = t * 32 + kk;
    int sec = k / HP, ksec = k % HP;
    float v = (n < H && ksec < H) ? W[((long)sec * H + ksec) * H + n] : 0.f;
    Wt[idx] = f2bf(v);
}

// ---------------------------------------------------------------------------
// Input feature conversion: X fp32 [rows][Kact] -> Y bf16 [rows][160] linear
// ---------------------------------------------------------------------------
__global__ __launch_bounds__(256)
void conv_in(const float* __restrict__ X, int rows, int Kact,
             unsigned short* __restrict__ Y){
    int t = blockIdx.x * 256 + threadIdx.x;
    if (t >= rows * 20) return;
    int row = t / 20, c = t % 20;
    int k0 = c * 8;
    bf8 v;
    #pragma unroll
    for (int j = 0; j < 8; j++){
        int k = k0 + j;
        float f = (k < Kact) ? X[(long)row * Kact + k] : 0.f;
        v[j] = (short)f2bf(f);
    }
    *(bf8*)(Y + (long)row * 160 + k0) = v;
}

// ---------------------------------------------------------------------------
// B-stationary persistent GEMM:  out = epi( A[rows][RL] @ W^T ), BN-half=160
// grid = 256 (1 block/CU). Block owns N-half; B-half (RL x 160, k-major)
// lives in LDS for the whole kernel -> K-loop has ZERO global loads.
// A tiles REG-STAGED (coalesced dwordx4, no global_load_lds fetch
// amplification), cross-tile double-buffered: loadSt(t+1) in flight across
// K-loop(t). (256,1) -> 512-reg cap, st[5] live across K-loop is safe.
// EPI: 0 = relu, 1 = raw.
// ---------------------------------------------------------------------------
template<int RL, int BM, int EPI>
__global__ __launch_bounds__(256, 1)
void bstat_k(const unsigned short* __restrict__ A,    // linear [rows][RL]
             const unsigned short* __restrict__ Wt,   // k-major [T][320][32]
             unsigned short* __restrict__ outb,       // linear [rows][320]
             int nTiles)
{
    constexpr int T     = RL / 32;         // K-steps (5 or 10)
    constexpr int MF    = BM / 32;         // M frags per wave (1 or 2)
    constexpr int TILEB = BM * RL * 2;     // 20480 both configs

    __shared__ char ldsB[T * 10240];       // [T][4][160][16B] : 50/100 KB
    __shared__ char ldsA[2][TILEB];        // 2 x 20KB

    const int tid  = threadIdx.x;
    const int w    = tid >> 6;
    const int wm   = w >> 1, wn = w & 1;   // 2M x 2N wave grid
    const int lane = tid & 63;
    const int lr   = lane & 15;
    const int g    = lane >> 4;
    const int nh   = blockIdx.x & 1;       // N-half

    // ---- B half -> LDS, once. layout [t][g][n][16B] ----
    for (int idx = tid; idx < T * 640; idx += 256){
        int t  = idx / 640;
        int r  = idx - t * 640;
        int gg = r / 160;
        int n  = r - gg * 160;
        bf8 v = *(const bf8*)(Wt + ((long)t * 320 + nh * 160 + n) * 32 + gg * 8);
        *(bf8*)(ldsB + (long)idx * 16) = v;
    }

    bf8 st[5];                             // staging regs (live across K-loop;
                                           // (256,1) -> no cap -> no spill)
    auto loadSt = [&](int t){
        const char* g0 = (const char*)A + (long)t * TILEB + tid * 16;
        #pragma unroll
        for (int rd = 0; rd < 5; rd++)
            st[rd] = *(const bf8*)(g0 + rd * 4096);
    };
    auto writeSt = [&](int buf){
        char* l0 = ldsA[buf] + tid * 16;
        #pragma unroll
        for (int rd = 0; rd < 5; rd++)
            *(bf8*)(l0 + rd * 4096) = st[rd];
    };

    int tile = blockIdx.x >> 1;
    if (tile >= nTiles) return;
    loadSt(tile);
    writeSt(0);
    __syncthreads();                        // B + first A tile visible

    int buf = 0;
    for (; tile < nTiles; tile += 128){
        int nt = tile + 128;
        const bool hn = (nt < nTiles);
        if (hn) loadSt(nt);                 // lands during this K-loop

        f4 acc[MF][5];
        #pragma unroll
        for (int mf = 0; mf < MF; mf++)
            #pragma unroll
            for (int nf = 0; nf < 5; nf++)
                acc[mf][nf] = (f4){0.f, 0.f, 0.f, 0.f};

        #pragma unroll
        for (int t = 0; t < T; t++){
            bf8 bfr[5], af[MF];
            const char* bb = ldsB + (((t * 4 + g) * 160) + wn * 80 + lr) * 16;
            #pragma unroll
            for (int nf = 0; nf < 5; nf++)
                bfr[nf] = *(const bf8*)(bb + nf * 256);
            #pragma unroll
            for (int mf = 0; mf < MF; mf++){
                int row = wm * (BM / 2) + mf * 16 + lr;
                af[mf] = *(const bf8*)(ldsA[buf] + row * (RL * 2) + (t * 4 + g) * 16);
            }
            #pragma unroll
            for (int mf = 0; mf < MF; mf++)
                #pragma unroll
                for (int nf = 0; nf < 5; nf++)
                    acc[mf][nf] = __builtin_amdgcn_mfma_f32_16x16x32_bf16(
                        bfr[nf], af[mf], acc[mf][nf], 0, 0, 0);
        }

        if (hn) writeSt(buf ^ 1);           // st dies here (loads returned);
                                            // buf^1 readers done at prev barrier

        // epilogue: D^T -> lane holds row, 4 consecutive cols
        #pragma unroll
        for (int mf = 0; mf < MF; mf++){
            const long row = (long)tile * BM + wm * (BM / 2) + mf * 16 + lr;
            #pragma unroll
            for (int nf = 0; nf < 5; nf++){
                const int colg = nh * 160 + wn * 80 + nf * 16 + g * 4;
                s4 v4;
                #pragma unroll
                for (int q = 0; q < 4; q++){
                    float v = acc[mf][nf][q];
                    if constexpr (EPI == 0) v = fmaxf(v, 0.f);
                    v4[q] = (short)f2bf(v);
                }
                *(s4*)(outb + row * HP + colg) = v4;
            }
        }
        __syncthreads();                    // next tile's LDS image ready
        buf ^= 1;
    }
}

// ---------------------------------------------------------------------------
// Wo GEMM, fused product, SECTION-FENCED (anti-spill, r19-proven):
//   atom_h = relu(input_atom@W0 + amsg@W1 + (input_atom*amsg)@W2 + b_o)
// ---------------------------------------------------------------------------
__global__ __launch_bounds__(256, 4)
void gemm_wo(const unsigned short* __restrict__ A0,   // input_atom [rows][320]
             const unsigned short* __restrict__ A1,   // amsg       [rows][320]
             const unsigned short* __restrict__ Wt,   // k-major [30][320][32]
             const float* __restrict__ b_o,
             unsigned short* __restrict__ outb,       // linear [rows][320]
             int nTiles)
{
    __shared__ char lds0[32 * 640];        // XOR-swizzled
    __shared__ char lds1[32 * 640];

    const int tid  = threadIdx.x;
    const int w    = tid >> 6;             // N stripe of 80
    const int lane = tid & 63;
    const int lr   = lane & 15;
    const int g    = lane >> 4;

    int tile = blockIdx.x;
    if (tile >= nTiles) return;
    const long rowBase = (long)tile * 32;

    auto stageA = [&](const unsigned short* src, char* dst){
        const char* gb = (const char*)(src + rowBase * HP);
        bf8 st[5];                          // transient: dead before K-loop
        #pragma unroll
        for (int i = 0; i < 5; i++)
            st[i] = *(const bf8*)(gb + (i * 256 + tid) * 16);
        #pragma unroll
        for (int i = 0; i < 5; i++){
            int f = i * 256 + tid;
            int row = f / 40, c = f % 40;
            *(bf8*)(dst + row * 640 + ((c ^ (row & 7)) << 4)) = st[i];
        }
    };

    bf8 bb[2][5];
    auto loadB = [&](int t, bf8 (&dst)[5]){
        const unsigned short* base = Wt + ((long)t * 320) * 32 + g * 8;
        #pragma unroll
        for (int n = 0; n < 5; n++)
            dst[n] = *(const bf8*)(base + (w * 80 + n * 16 + lr) * 32);
    };

    stageA(A0, lds0);
    stageA(A1, lds1);
    loadB(0, bb[0]);                        // latency hides under stage drain
    __syncthreads();                        // LDS read-only after this

    f4 acc[2][5];
    #pragma unroll
    for (int m = 0; m < 2; m++)
        #pragma unroll
        for (int n = 0; n < 5; n++)
            acc[m][n] = (f4){0.f, 0.f, 0.f, 0.f};

    #pragma unroll
    for (int sec = 0; sec < 3; ++sec){
        if (sec > 0){
            __syncthreads();               // scheduling fence (anti-spill)
            loadB(sec * 10, bb[0]);
        }
        loadB(sec * 10 + 1, bb[1]);

        #pragma unroll
        for (int i = 0; i < 10; i++){
            bf8 af[2];
            #pragma unroll
            for (int m = 0; m < 2; m++){
                const int row = m * 16 + lr;
                const int off = row * 640 + (((i * 4 + g) ^ (row & 7)) << 4);
                if (sec == 0){
                    af[m] = *(const bf8*)(lds0 + off);
                } else if (sec == 1){
                    af[m] = *(const bf8*)(lds1 + off);
                } else {
                    bf8 a = *(const bf8*)(lds0 + off);
                    bf8 b = *(const bf8*)(lds1 + off);
                    #pragma unroll
                    for (int q = 0; q < 8; q++)
                        af[m][q] = (short)f2bf(bf2f((unsigned short)a[q]) *
                                               bf2f((unsigned short)b[q]));
                }
            }
            #pragma unroll
            for (int m = 0; m < 2; m++)
                #pragma unroll
                for (int n = 0; n < 5; n++)
                    acc[m][n] = __builtin_amdgcn_mfma_f32_16x16x32_bf16(
                        bb[i & 1][n], af[m], acc[m][n], 0, 0, 0);
            if (i + 2 < 10) loadB(sec * 10 + i + 2, bb[i & 1]);
        }
    }

    // epilogue: D^T -> lane holds row, 4 consecutive cols; + b_o, relu
    #pragma unroll
    for (int m = 0; m < 2; m++){
        const long row = rowBase + m * 16 + lr;
        #pragma unroll
        for (int n = 0; n < 5; n++){
            const int colg = w * 80 + n * 16 + g * 4;
            s4 v4;
            #pragma unroll
            for (int q = 0; q < 4; q++){
                int col = colg + q;
                float v = acc[m][n][q];
                v += (col < H ? b_o[col] : 0.f);
                v4[q] = (short)f2bf(fmaxf(v, 0.f));
            }
            *(s4*)(outb + row * HP + colg) = v4;
        }
    }
}

// ---------------------------------------------------------------------------
// comb: msg'[e] = relu(bond_in[e] + sum_{j in bucket[src[e]]} MW[j] - MW[rev[e]])
// thread = (bond, 16B chunk); 6 independent loads in flight. Linear layout.
// ---------------------------------------------------------------------------
__global__ __launch_bounds__(256)
void comb_k(const unsigned short* __restrict__ MW,
            const unsigned short* __restrict__ bond_in,
            const int* __restrict__ b_src, const int* __restrict__ b2revb,
            const int* __restrict__ cnt, const int* __restrict__ bucket,
            unsigned short* __restrict__ out, int nB){
    int t = blockIdx.x * 256 + threadIdx.x;
    if (t >= nB * 40) return;
    int e = t / 40, ch = t % 40;
    int k0 = ch * 8;
    int s   = b_src[e];
    int rev = b2revb[e];
    int dg = cnt[s]; if (dg > CAP) dg = CAP;
    long base = (long)s * CAP;
    int be0 = 0, be1 = 0, be2 = 0, be3 = 0;
    if (dg > 0) be0 = bucket[base + 0];
    if (dg > 1) be1 = bucket[base + 1];
    if (dg > 2) be2 = bucket[base + 2];
    if (dg > 3) be3 = bucket[base + 3];
    bf8 bi = *(const bf8*)(bond_in + (long)e * HP + k0);
    bf8 rv = *(const bf8*)(MW + (long)rev * HP + k0);
    bf8 m0, m1, m2, m3;
    if (dg > 0) m0 = *(const bf8*)(MW + (long)be0 * HP + k0);
    if (dg > 1) m1 = *(const bf8*)(MW + (long)be1 * HP + k0);
    if (dg > 2) m2 = *(const bf8*)(MW + (long)be2 * HP + k0);
    if (dg > 3) m3 = *(const bf8*)(MW + (long)be3 * HP + k0);
    float sacc[8];
    #pragma unroll
    for (int q = 0; q < 8; q++)
        sacc[q] = bf2f((unsigned short)bi[q]) - bf2f((unsigned short)rv[q]);
    auto addv = [&](bf8 mm){
        #pragma unroll
        for (int q = 0; q < 8; q++) sacc[q] += bf2f((unsigned short)mm[q]);
    };
    if (dg > 0) addv(m0);
    if (dg > 1) addv(m1);
    if (dg > 2) addv(m2);
    if (dg > 3) addv(m3);
    for (int j = 4; j < dg; ++j){
        int be = bucket[base + j];
        addv(*(const bf8*)(MW + (long)be * HP + k0));
    }
    bf8 v;
    #pragma unroll
    for (int q = 0; q < 8; q++) v[q] = (short)f2bf(fmaxf(sacc[q], 0.f));
    *(bf8*)(out + (long)e * HP + k0) = v;
}

// ---------------------------------------------------------------------------
// a_msg[a] = sum of msg rows with dst==a (bf16, linear)
// ---------------------------------------------------------------------------
__global__ __launch_bounds__(256)
void amsg_k(const unsigned short* __restrict__ msg, const int* __restrict__ cnt,
            const int* __restrict__ bucket,
            unsigned short* __restrict__ amsg, int nA){
    int t = blockIdx.x * 256 + threadIdx.x;
    if (t >= nA * 40) return;
    int a = t / 40, ch = t % 40;
    int k0 = ch * 8;
    int dg = cnt[a]; if (dg > CAP) dg = CAP;
    long base = (long)a * CAP;
    int be0 = 0, be1 = 0, be2 = 0, be3 = 0;
    if (dg > 0) be0 = bucket[base + 0];
    if (dg > 1) be1 = bucket[base + 1];
    if (dg > 2) be2 = bucket[base + 2];
    if (dg > 3) be3 = bucket[base + 3];
    bf8 m0, m1, m2, m3;
    if (dg > 0) m0 = *(const bf8*)(msg + (long)be0 * HP + k0);
    if (dg > 1) m1 = *(const bf8*)(msg + (long)be1 * HP + k0);
    if (dg > 2) m2 = *(const bf8*)(msg + (long)be2 * HP + k0);
    if (dg > 3) m3 = *(const bf8*)(msg + (long)be3 * HP + k0);
    float s[8];
    #pragma unroll
    for (int q = 0; q < 8; q++) s[q] = 0.f;
    auto addv = [&](bf8 mm){
        #pragma unroll
        for (int q = 0; q < 8; q++) s[q] += bf2f((unsigned short)mm[q]);
    };
    if (dg > 0) addv(m0);
    if (dg > 1) addv(m1);
    if (dg > 2) addv(m2);
    if (dg > 3) addv(m3);
    for (int j = 4; j < dg; ++j)
        addv(*(const bf8*)(msg + (long)bucket[base + j] * HP + k0));
    bf8 va;
    #pragma unroll
    for (int q = 0; q < 8; q++) va[q] = (short)f2bf(s[q]);
    *(bf8*)(amsg + (long)a * HP + k0) = va;
}

// ---------------------------------------------------------------------------
// Readout: per-molecule mean over sorted mol_ids (binary-search range)
// ---------------------------------------------------------------------------
__global__ __launch_bounds__(320)
void readout_k(const unsigned short* __restrict__ atom_h,
               const int* __restrict__ mol_ids, int nAtoms,
               float* __restrict__ out){
    int m = blockIdx.x;
    int t = threadIdx.x;
    int lo = 0, hi = nAtoms;
    while (lo < hi){ int mid = (lo + hi) >> 1; if (mol_ids[mid] < m) lo = mid + 1; else hi = mid; }
    int lo2 = lo, hi2 = nAtoms;
    while (lo2 < hi2){ int mid = (lo2 + hi2) >> 1; if (mol_ids[mid] < m + 1) lo2 = mid + 1; else hi2 = mid; }
    if (t < H){
        float s = 0.f;
        for (int a = lo; a < lo2; ++a) s += bf2f(atom_h[(long)a * HP + t]);
        int c2 = lo2 - lo;
        out[(long)m * H + t] = s / (float)(c2 > 0 ? c2 : 1);
    }
}

// ---------------------------------------------------------------------------
extern "C" void kernel_launch(void* const* d_in, const int* in_sizes, int n_in,
                              void* d_out, int out_size, void* d_ws, size_t ws_size,
                              hipStream_t stream){
    const float* f_atoms  = (const float*)d_in[0];
    const float* f_bonds  = (const float*)d_in[1];
    const float* W_i_atom = (const float*)d_in[2];
    const float* W_i_bond = (const float*)d_in[3];
    const float* W_h      = (const float*)d_in[4];
    const float* W_o      = (const float*)d_in[5];
    const float* b_o      = (const float*)d_in[6];
    const int* b_src   = (const int*)d_in[7];
    const int* b_dst   = (const int*)d_in[8];
    const int* b2revb  = (const int*)d_in[9];
    const int* mol_ids = (const int*)d_in[10];

    const int nA = in_sizes[10];          // 200000
    const int nB = in_sizes[7];           // 400000
    const int nM = out_size / H;          // 4096

    char* p = (char*)d_ws;
    auto alloc = [&](size_t bytes){ char* q = p; p += (bytes + 255) & ~(size_t)255; return q; };
    unsigned short* Wt_ia = (unsigned short*)alloc((size_t)320 * 160 * 2);
    unsigned short* Wt_ib = (unsigned short*)alloc((size_t)320 * 160 * 2);
    unsigned short* Wt_h  = (unsigned short*)alloc((size_t)3 * 320 * 320 * 2);
    unsigned short* Wt_o  = (unsigned short*)alloc((size_t)320 * 960 * 2);
    int* cnt    = (int*)alloc((size_t)nA * 4);
    int* bucket = (int*)alloc((size_t)nA * CAP * 4);
    unsigned short* input_atom = (unsigned short*)alloc((size_t)nA * HP * 2);
    unsigned short* input_bond = (unsigned short*)alloc((size_t)nB * HP * 2);
    unsigned short* msgA = (unsigned short*)alloc((size_t)nB * HP * 2);
    unsigned short* MW   = (unsigned short*)alloc((size_t)nB * HP * 2);
    // aliases into dead regions:
    unsigned short* fa_bf  = MW;                                  // [nA][160]
    unsigned short* fb_bf  = MW + (size_t)nA * 160;               // [nB][160]
    unsigned short* amsg   = MW;                                  // MW dead after comb3
    unsigned short* atom_h = input_bond;                          // dead after comb3

    if ((size_t)(p - (char*)d_ws) > ws_size) return;  // diagnostic: ws too small

    // adjacency buckets
    hipMemsetAsync(cnt, 0, (size_t)nA * 4, stream);
    fill_k<<<dim3((nB + 255) / 256), dim3(256), 0, stream>>>(b_dst, cnt, bucket, nB);

    // weight prep (k-major) + input conversion (linear)
    prep_wt<<<dim3((320*160 + 255)/256), dim3(256), 0, stream>>>(W_i_atom, Wt_ia, 133, 160);
    prep_wt<<<dim3((320*160 + 255)/256), dim3(256), 0, stream>>>(W_i_bond, Wt_ib, 147, 160);
    for (int d = 0; d < 3; d++)
        prep_wt<<<dim3((320*320 + 255)/256), dim3(256), 0, stream>>>(
            W_h + (size_t)d * H * H, Wt_h + (size_t)d * 320 * 320, 300, 320);
    prep_wto<<<dim3((320*960 + 255)/256), dim3(256), 0, stream>>>(W_o, Wt_o);
    conv_in<<<dim3((nA*20 + 255)/256), dim3(256), 0, stream>>>(f_atoms, nA, 133, fa_bf);
    conv_in<<<dim3((nB*20 + 255)/256), dim3(256), 0, stream>>>(f_bonds, nB, 147, fb_bf);

    // input projections (B-stationary, RL=160, BM=64)
    bstat_k<160,64,0><<<dim3(256), dim3(256), 0, stream>>>(
        fa_bf, Wt_ia, input_atom, nA / 64);
    bstat_k<160,64,0><<<dim3(256), dim3(256), 0, stream>>>(
        fb_bf, Wt_ib, input_bond, nB / 64);

    // message steps: MW = msg @ W_h[d]; msg' = relu(bond_in + bucket-sum - rev)
    const int combGrid = (nB * 40 + 255) / 256;
    const unsigned short* msg_cur = input_bond;
    for (int d = 0; d < 3; d++){
        bstat_k<320,32,1><<<dim3(256), dim3(256), 0, stream>>>(
            msg_cur, Wt_h + (size_t)d * 320 * 320, MW, nB / 32);
        comb_k<<<dim3(combGrid), dim3(256), 0, stream>>>(
            MW, input_bond, b_src, b2revb, cnt, bucket, msgA, nB);
        msg_cur = msgA;
    }

    // final per-atom aggregation (linear, no prod materialization)
    amsg_k<<<dim3((nA * 40 + 255) / 256), dim3(256), 0, stream>>>(
        msgA, cnt, bucket, amsg, nA);

    // atom_h = relu([input_atom | amsg | input_atom*amsg] @ W_o + b_o)
    // product fused in-kernel; three fenced 10-step sections (anti-spill)
    gemm_wo<<<dim3(nA / 32), dim3(256), 0, stream>>>(
        input_atom, amsg, Wt_o, b_o, atom_h, nA / 32);

    // per-molecule mean
    readout_k<<<dim3(nM), dim3(320), 0, stream>>>(atom_h, mol_ids, nA, (float*)d_out);
}

// Round 23
// 1959.946 us; speedup vs baseline: 1.3408x; 1.0024x over previous
//
#include <hip/hip_runtime.h>
#include <stdint.h>

#define H   300
#define HP  320
#define CAP 32     // max incoming bonds per atom (Binomial(400k,1/200k) max ~13)

using bf8 = __attribute__((ext_vector_type(8))) short;   // 8 x bf16
using s4  = __attribute__((ext_vector_type(4))) short;   // 4 x bf16 (8B store)
using f4  = __attribute__((ext_vector_type(4))) float;   // MFMA acc

__device__ __forceinline__ float bf2f(unsigned short u){
    union { unsigned int i; float f; } v; v.i = ((unsigned int)u) << 16; return v.f;
}
__device__ __forceinline__ unsigned short f2bf(float x){
    unsigned int u = __builtin_bit_cast(unsigned int, x);
    u = (u + 0x7FFFu + ((u >> 16) & 1u)) >> 16;   // RNE
    return (unsigned short)u;
}

// ---------------------------------------------------------------------------
// Incoming-bond bucket list: bucket[a][0..cnt[a]) = bond indices with dst==a
// ---------------------------------------------------------------------------
__global__ void fill_k(const int* __restrict__ b_dst, int* __restrict__ cnt,
                       int* __restrict__ bucket, int nB){
    int e = blockIdx.x * 256 + threadIdx.x;
    if (e >= nB) return;
    int d = b_dst[e];
    int slot = atomicAdd(&cnt[d], 1);
    if (slot < CAP) bucket[(long)d * CAP + slot] = e;
}

// ---------------------------------------------------------------------------
// Weight prep: W [Kact][H] fp32 -> Wt k-major [Ktot/32][320][32] bf16
// ---------------------------------------------------------------------------
__global__ void prep_wt(const float* __restrict__ W, unsigned short* __restrict__ Wt,
                        int Kact, int Kp){
    int idx = blockIdx.x * 256 + threadIdx.x;
    if (idx >= 320 * Kp) return;
    int t  = idx / (320 * 32);
    int r  = idx % (320 * 32);
    int n  = r / 32, kk = r % 32;
    int k  = t * 32 + kk;
    float v = (n < H && k < Kact) ? W[(long)k * H + n] : 0.f;
    Wt[idx] = f2bf(v);
}

// W_o [900][300] -> k-major [30][320][32]; k = t*32+kk, sec = k/320
__global__ void prep_wto(const float* __restrict__ W, unsigned short* __restrict__ Wt){
    int idx = blockIdx.x * 256 + threadIdx.x;
    if (idx >= 320 * 960) return;
    int t  = idx / (320 * 32);
    int r  = idx % (320 * 32);
    int n  = r / 32, kk = r % 32;
    int k  = t * 32 + kk;
    int sec = k / HP, ksec = k % HP;
    float v = (n < H && ksec < H) ? W[((long)sec * H + ksec) * H + n] : 0.f;
    Wt[idx] = f2bf(v);
}

// ---------------------------------------------------------------------------
// Input feature conversion: X fp32 [rows][Kact] -> Y bf16 [rows][160] linear
// ---------------------------------------------------------------------------
__global__ __launch_bounds__(256)
void conv_in(const float* __restrict__ X, int rows, int Kact,
             unsigned short* __restrict__ Y){
    int t = blockIdx.x * 256 + threadIdx.x;
    if (t >= rows * 20) return;
    int row = t / 20, c = t % 20;
    int k0 = c * 8;
    bf8 v;
    #pragma unroll
    for (int j = 0; j < 8; j++){
        int k = k0 + j;
        float f = (k < Kact) ? X[(long)row * Kact + k] : 0.f;
        v[j] = (short)f2bf(f);
    }
    *(bf8*)(Y + (long)row * 160 + k0) = v;
}

// ---------------------------------------------------------------------------
// B-stationary persistent GEMM:  out = epi( A[rows][RL] @ W^T ), BN-half=160
// grid = 256 (1 block/CU). Block owns N-half; B-half (RL x 160, k-major)
// lives in LDS for the whole kernel -> K-loop has ZERO global loads.
// A tiles REG-STAGED (coalesced dwordx4), cross-tile double-buffered:
// loadSt(t+1) in flight across K-loop(t). (256,1) -> no reg cap -> no spill.
// LDS A image XOR-SWIZZLED (c ^= row&XM): af ds_read 16-way conflict -> 2/4-way.
// EPI: 0 = relu, 1 = raw.
// ---------------------------------------------------------------------------
template<int RL, int BM, int EPI>
__global__ __launch_bounds__(256, 1)
void bstat_k(const unsigned short* __restrict__ A,    // linear [rows][RL]
             const unsigned short* __restrict__ Wt,   // k-major [T][320][32]
             unsigned short* __restrict__ outb,       // linear [rows][320]
             int nTiles)
{
    constexpr int T      = RL / 32;        // K-steps (5 or 10)
    constexpr int MF     = BM / 32;        // M frags per wave (1 or 2)
    constexpr int TILEB  = BM * RL * 2;    // 20480 both configs
    constexpr int CHUNKS = RL / 8;         // 16B chunks per row (40 or 20)
    constexpr int XM     = (CHUNKS % 8 == 0) ? 7 : 3;   // in-row XOR mask

    __shared__ char ldsB[T * 10240];       // [T][4][160][16B] : 50/100 KB
    __shared__ char ldsA[2][TILEB];        // 2 x 20KB, swizzled rows

    const int tid  = threadIdx.x;
    const int w    = tid >> 6;
    const int wm   = w >> 1, wn = w & 1;   // 2M x 2N wave grid
    const int lane = tid & 63;
    const int lr   = lane & 15;
    const int g    = lane >> 4;
    const int nh   = blockIdx.x & 1;       // N-half

    // ---- B half -> LDS, once. layout [t][g][n][16B] ----
    for (int idx = tid; idx < T * 640; idx += 256){
        int t  = idx / 640;
        int r  = idx - t * 640;
        int gg = r / 160;
        int n  = r - gg * 160;
        bf8 v = *(const bf8*)(Wt + ((long)t * 320 + nh * 160 + n) * 32 + gg * 8);
        *(bf8*)(ldsB + (long)idx * 16) = v;
    }

    bf8 st[5];                             // staging regs (live across K-loop;
                                           // (256,1) -> no cap -> no spill)
    auto loadSt = [&](int t){
        const char* g0 = (const char*)A + (long)t * TILEB + tid * 16;
        #pragma unroll
        for (int rd = 0; rd < 5; rd++)
            st[rd] = *(const bf8*)(g0 + rd * 4096);
    };
    auto writeSt = [&](int buf){
        #pragma unroll
        for (int rd = 0; rd < 5; rd++){
            int f = rd * 256 + tid;
            int row = f / CHUNKS, c = f % CHUNKS;
            *(bf8*)(ldsA[buf] + row * (RL * 2) + ((c ^ (row & XM)) << 4)) = st[rd];
        }
    };

    int tile = blockIdx.x >> 1;
    if (tile >= nTiles) return;
    loadSt(tile);
    writeSt(0);
    __syncthreads();                        // B + first A tile visible

    int buf = 0;
    for (; tile < nTiles; tile += 128){
        int nt = tile + 128;
        const bool hn = (nt < nTiles);
        if (hn) loadSt(nt);                 // lands during this K-loop

        f4 acc[MF][5];
        #pragma unroll
        for (int mf = 0; mf < MF; mf++)
            #pragma unroll
            for (int nf = 0; nf < 5; nf++)
                acc[mf][nf] = (f4){0.f, 0.f, 0.f, 0.f};

        #pragma unroll
        for (int t = 0; t < T; t++){
            bf8 bfr[5], af[MF];
            const char* bb = ldsB + (((t * 4 + g) * 160) + wn * 80 + lr) * 16;
            #pragma unroll
            for (int nf = 0; nf < 5; nf++)
                bfr[nf] = *(const bf8*)(bb + nf * 256);
            #pragma unroll
            for (int mf = 0; mf < MF; mf++){
                int row = wm * (BM / 2) + mf * 16 + lr;
                int ch  = t * 4 + g;
                af[mf] = *(const bf8*)(ldsA[buf] + row * (RL * 2)
                                       + ((ch ^ (row & XM)) << 4));
            }
            #pragma unroll
            for (int mf = 0; mf < MF; mf++)
                #pragma unroll
                for (int nf = 0; nf < 5; nf++)
                    acc[mf][nf] = __builtin_amdgcn_mfma_f32_16x16x32_bf16(
                        bfr[nf], af[mf], acc[mf][nf], 0, 0, 0);
        }

        if (hn) writeSt(buf ^ 1);           // st dies here (loads returned);
                                            // buf^1 readers done at prev barrier

        // epilogue: D^T -> lane holds row, 4 consecutive cols
        #pragma unroll
        for (int mf = 0; mf < MF; mf++){
            const long row = (long)tile * BM + wm * (BM / 2) + mf * 16 + lr;
            #pragma unroll
            for (int nf = 0; nf < 5; nf++){
                const int colg = nh * 160 + wn * 80 + nf * 16 + g * 4;
                s4 v4;
                #pragma unroll
                for (int q = 0; q < 4; q++){
                    float v = acc[mf][nf][q];
                    if constexpr (EPI == 0) v = fmaxf(v, 0.f);
                    v4[q] = (short)f2bf(v);
                }
                *(s4*)(outb + row * HP + colg) = v4;
            }
        }
        __syncthreads();                    // next tile's LDS image ready
        buf ^= 1;
    }
}

// ---------------------------------------------------------------------------
// Wo GEMM, fused product, SECTION-FENCED (anti-spill, r19-proven):
//   atom_h = relu(input_atom@W0 + amsg@W1 + (input_atom*amsg)@W2 + b_o)
// ---------------------------------------------------------------------------
__global__ __launch_bounds__(256, 4)
void gemm_wo(const unsigned short* __restrict__ A0,   // input_atom [rows][320]
             const unsigned short* __restrict__ A1,   // amsg       [rows][320]
             const unsigned short* __restrict__ Wt,   // k-major [30][320][32]
             const float* __restrict__ b_o,
             unsigned short* __restrict__ outb,       // linear [rows][320]
             int nTiles)
{
    __shared__ char lds0[32 * 640];        // XOR-swizzled
    __shared__ char lds1[32 * 640];

    const int tid  = threadIdx.x;
    const int w    = tid >> 6;             // N stripe of 80
    const int lane = tid & 63;
    const int lr   = lane & 15;
    const int g    = lane >> 4;

    int tile = blockIdx.x;
    if (tile >= nTiles) return;
    const long rowBase = (long)tile * 32;

    auto stageA = [&](const unsigned short* src, char* dst){
        const char* gb = (const char*)(src + rowBase * HP);
        bf8 st[5];                          // transient: dead before K-loop
        #pragma unroll
        for (int i = 0; i < 5; i++)
            st[i] = *(const bf8*)(gb + (i * 256 + tid) * 16);
        #pragma unroll
        for (int i = 0; i < 5; i++){
            int f = i * 256 + tid;
            int row = f / 40, c = f % 40;
            *(bf8*)(dst + row * 640 + ((c ^ (row & 7)) << 4)) = st[i];
        }
    };

    bf8 bb[2][5];
    auto loadB = [&](int t, bf8 (&dst)[5]){
        const unsigned short* base = Wt + ((long)t * 320) * 32 + g * 8;
        #pragma unroll
        for (int n = 0; n < 5; n++)
            dst[n] = *(const bf8*)(base + (w * 80 + n * 16 + lr) * 32);
    };

    stageA(A0, lds0);
    stageA(A1, lds1);
    loadB(0, bb[0]);                        // latency hides under stage drain
    __syncthreads();                        // LDS read-only after this

    f4 acc[2][5];
    #pragma unroll
    for (int m = 0; m < 2; m++)
        #pragma unroll
        for (int n = 0; n < 5; n++)
            acc[m][n] = (f4){0.f, 0.f, 0.f, 0.f};

    #pragma unroll
    for (int sec = 0; sec < 3; ++sec){
        if (sec > 0){
            __syncthreads();               // scheduling fence (anti-spill)
            loadB(sec * 10, bb[0]);
        }
        loadB(sec * 10 + 1, bb[1]);

        #pragma unroll
        for (int i = 0; i < 10; i++){
            bf8 af[2];
            #pragma unroll
            for (int m = 0; m < 2; m++){
                const int row = m * 16 + lr;
                const int off = row * 640 + (((i * 4 + g) ^ (row & 7)) << 4);
                if (sec == 0){
                    af[m] = *(const bf8*)(lds0 + off);
                } else if (sec == 1){
                    af[m] = *(const bf8*)(lds1 + off);
                } else {
                    bf8 a = *(const bf8*)(lds0 + off);
                    bf8 b = *(const bf8*)(lds1 + off);
                    #pragma unroll
                    for (int q = 0; q < 8; q++)
                        af[m][q] = (short)f2bf(bf2f((unsigned short)a[q]) *
                                               bf2f((unsigned short)b[q]));
                }
            }
            #pragma unroll
            for (int m = 0; m < 2; m++)
                #pragma unroll
                for (int n = 0; n < 5; n++)
                    acc[m][n] = __builtin_amdgcn_mfma_f32_16x16x32_bf16(
                        bb[i & 1][n], af[m], acc[m][n], 0, 0, 0);
            if (i + 2 < 10) loadB(sec * 10 + i + 2, bb[i & 1]);
        }
    }

    // epilogue: D^T -> lane holds row, 4 consecutive cols; + b_o, relu
    #pragma unroll
    for (int m = 0; m < 2; m++){
        const long row = rowBase + m * 16 + lr;
        #pragma unroll
        for (int n = 0; n < 5; n++){
            const int colg = w * 80 + n * 16 + g * 4;
            s4 v4;
            #pragma unroll
            for (int q = 0; q < 4; q++){
                int col = colg + q;
                float v = acc[m][n][q];
                v += (col < H ? b_o[col] : 0.f);
                v4[q] = (short)f2bf(fmaxf(v, 0.f));
            }
            *(s4*)(outb + row * HP + colg) = v4;
        }
    }
}

// ---------------------------------------------------------------------------
// comb: msg'[e] = relu(bond_in[e] + sum_{j in bucket[src[e]]} MW[j] - MW[rev[e]])
// thread = (bond, 16B chunk); 6 independent loads in flight. Linear layout.
// ---------------------------------------------------------------------------
__global__ __launch_bounds__(256)
void comb_k(const unsigned short* __restrict__ MW,
            const unsigned short* __restrict__ bond_in,
            const int* __restrict__ b_src, const int* __restrict__ b2revb,
            const int* __restrict__ cnt, const int* __restrict__ bucket,
            unsigned short* __restrict__ out, int nB){
    int t = blockIdx.x * 256 + threadIdx.x;
    if (t >= nB * 40) return;
    int e = t / 40, ch = t % 40;
    int k0 = ch * 8;
    int s   = b_src[e];
    int rev = b2revb[e];
    int dg = cnt[s]; if (dg > CAP) dg = CAP;
    long base = (long)s * CAP;
    int be0 = 0, be1 = 0, be2 = 0, be3 = 0;
    if (dg > 0) be0 = bucket[base + 0];
    if (dg > 1) be1 = bucket[base + 1];
    if (dg > 2) be2 = bucket[base + 2];
    if (dg > 3) be3 = bucket[base + 3];
    bf8 bi = *(const bf8*)(bond_in + (long)e * HP + k0);
    bf8 rv = *(const bf8*)(MW + (long)rev * HP + k0);
    bf8 m0, m1, m2, m3;
    if (dg > 0) m0 = *(const bf8*)(MW + (long)be0 * HP + k0);
    if (dg > 1) m1 = *(const bf8*)(MW + (long)be1 * HP + k0);
    if (dg > 2) m2 = *(const bf8*)(MW + (long)be2 * HP + k0);
    if (dg > 3) m3 = *(const bf8*)(MW + (long)be3 * HP + k0);
    float sacc[8];
    #pragma unroll
    for (int q = 0; q < 8; q++)
        sacc[q] = bf2f((unsigned short)bi[q]) - bf2f((unsigned short)rv[q]);
    auto addv = [&](bf8 mm){
        #pragma unroll
        for (int q = 0; q < 8; q++) sacc[q] += bf2f((unsigned short)mm[q]);
    };
    if (dg > 0) addv(m0);
    if (dg > 1) addv(m1);
    if (dg > 2) addv(m2);
    if (dg > 3) addv(m3);
    for (int j = 4; j < dg; ++j){
        int be = bucket[base + j];
        addv(*(const bf8*)(MW + (long)be * HP + k0));
    }
    bf8 v;
    #pragma unroll
    for (int q = 0; q < 8; q++) v[q] = (short)f2bf(fmaxf(sacc[q], 0.f));
    *(bf8*)(out + (long)e * HP + k0) = v;
}

// ---------------------------------------------------------------------------
// a_msg[a] = sum of msg rows with dst==a (bf16, linear)
// ---------------------------------------------------------------------------
__global__ __launch_bounds__(256)
void amsg_k(const unsigned short* __restrict__ msg, const int* __restrict__ cnt,
            const int* __restrict__ bucket,
            unsigned short* __restrict__ amsg, int nA){
    int t = blockIdx.x * 256 + threadIdx.x;
    if (t >= nA * 40) return;
    int a = t / 40, ch = t % 40;
    int k0 = ch * 8;
    int dg = cnt[a]; if (dg > CAP) dg = CAP;
    long base = (long)a * CAP;
    int be0 = 0, be1 = 0, be2 = 0, be3 = 0;
    if (dg > 0) be0 = bucket[base + 0];
    if (dg > 1) be1 = bucket[base + 1];
    if (dg > 2) be2 = bucket[base + 2];
    if (dg > 3) be3 = bucket[base + 3];
    bf8 m0, m1, m2, m3;
    if (dg > 0) m0 = *(const bf8*)(msg + (long)be0 * HP + k0);
    if (dg > 1) m1 = *(const bf8*)(msg + (long)be1 * HP + k0);
    if (dg > 2) m2 = *(const bf8*)(msg + (long)be2 * HP + k0);
    if (dg > 3) m3 = *(const bf8*)(msg + (long)be3 * HP + k0);
    float s[8];
    #pragma unroll
    for (int q = 0; q < 8; q++) s[q] = 0.f;
    auto addv = [&](bf8 mm){
        #pragma unroll
        for (int q = 0; q < 8; q++) s[q] += bf2f((unsigned short)mm[q]);
    };
    if (dg > 0) addv(m0);
    if (dg > 1) addv(m1);
    if (dg > 2) addv(m2);
    if (dg > 3) addv(m3);
    for (int j = 4; j < dg; ++j)
        addv(*(const bf8*)(msg + (long)bucket[base + j] * HP + k0));
    bf8 va;
    #pragma unroll
    for (int q = 0; q < 8; q++) va[q] = (short)f2bf(s[q]);
    *(bf8*)(amsg + (long)a * HP + k0) = va;
}

// ---------------------------------------------------------------------------
// Readout: per-molecule mean over sorted mol_ids (binary-search range)
// ---------------------------------------------------------------------------
__global__ __launch_bounds__(320)
void readout_k(const unsigned short* __restrict__ atom_h,
               const int* __restrict__ mol_ids, int nAtoms,
               float* __restrict__ out){
    int m = blockIdx.x;
    int t = threadIdx.x;
    int lo = 0, hi = nAtoms;
    while (lo < hi){ int mid = (lo + hi) >> 1; if (mol_ids[mid] < m) lo = mid + 1; else hi = mid; }
    int lo2 = lo, hi2 = nAtoms;
    while (lo2 < hi2){ int mid = (lo2 + hi2) >> 1; if (mol_ids[mid] < m + 1) lo2 = mid + 1; else hi2 = mid; }
    if (t < H){
        float s = 0.f;
        for (int a = lo; a < lo2; ++a) s += bf2f(atom_h[(long)a * HP + t]);
        int c2 = lo2 - lo;
        out[(long)m * H + t] = s / (float)(c2 > 0 ? c2 : 1);
    }
}

// ---------------------------------------------------------------------------
extern "C" void kernel_launch(void* const* d_in, const int* in_sizes, int n_in,
                              void* d_out, int out_size, void* d_ws, size_t ws_size,
                              hipStream_t stream){
    const float* f_atoms  = (const float*)d_in[0];
    const float* f_bonds  = (const float*)d_in[1];
    const float* W_i_atom = (const float*)d_in[2];
    const float* W_i_bond = (const float*)d_in[3];
    const float* W_h      = (const float*)d_in[4];
    const float* W_o      = (const float*)d_in[5];
    const float* b_o      = (const float*)d_in[6];
    const int* b_src   = (const int*)d_in[7];
    const int* b_dst   = (const int*)d_in[8];
    const int* b2revb  = (const int*)d_in[9];
    const int* mol_ids = (const int*)d_in[10];

    const int nA = in_sizes[10];          // 200000
    const int nB = in_sizes[7];           // 400000
    const int nM = out_size / H;          // 4096

    char* p = (char*)d_ws;
    auto alloc = [&](size_t bytes){ char* q = p; p += (bytes + 255) & ~(size_t)255; return q; };
    unsigned short* Wt_ia = (unsigned short*)alloc((size_t)320 * 160 * 2);
    unsigned short* Wt_ib = (unsigned short*)alloc((size_t)320 * 160 * 2);
    unsigned short* Wt_h  = (unsigned short*)alloc((size_t)3 * 320 * 320 * 2);
    unsigned short* Wt_o  = (unsigned short*)alloc((size_t)320 * 960 * 2);
    int* cnt    = (int*)alloc((size_t)nA * 4);
    int* bucket = (int*)alloc((size_t)nA * CAP * 4);
    unsigned short* input_atom = (unsigned short*)alloc((size_t)nA * HP * 2);
    unsigned short* input_bond = (unsigned short*)alloc((size_t)nB * HP * 2);
    unsigned short* msgA = (unsigned short*)alloc((size_t)nB * HP * 2);
    unsigned short* MW   = (unsigned short*)alloc((size_t)nB * HP * 2);
    // aliases into dead regions:
    unsigned short* fa_bf  = MW;                                  // [nA][160]
    unsigned short* fb_bf  = MW + (size_t)nA * 160;               // [nB][160]
    unsigned short* amsg   = MW;                                  // MW dead after comb3
    unsigned short* atom_h = input_bond;                          // dead after comb3

    if ((size_t)(p - (char*)d_ws) > ws_size) return;  // diagnostic: ws too small

    // adjacency buckets
    hipMemsetAsync(cnt, 0, (size_t)nA * 4, stream);
    fill_k<<<dim3((nB + 255) / 256), dim3(256), 0, stream>>>(b_dst, cnt, bucket, nB);

    // weight prep (k-major) + input conversion (linear)
    prep_wt<<<dim3((320*160 + 255)/256), dim3(256), 0, stream>>>(W_i_atom, Wt_ia, 133, 160);
    prep_wt<<<dim3((320*160 + 255)/256), dim3(256), 0, stream>>>(W_i_bond, Wt_ib, 147, 160);
    for (int d = 0; d < 3; d++)
        prep_wt<<<dim3((320*320 + 255)/256), dim3(256), 0, stream>>>(
            W_h + (size_t)d * H * H, Wt_h + (size_t)d * 320 * 320, 300, 320);
    prep_wto<<<dim3((320*960 + 255)/256), dim3(256), 0, stream>>>(W_o, Wt_o);
    conv_in<<<dim3((nA*20 + 255)/256), dim3(256), 0, stream>>>(f_atoms, nA, 133, fa_bf);
    conv_in<<<dim3((nB*20 + 255)/256), dim3(256), 0, stream>>>(f_bonds, nB, 147, fb_bf);

    // input projections (B-stationary, RL=160, BM=64)
    bstat_k<160,64,0><<<dim3(256), dim3(256), 0, stream>>>(
        fa_bf, Wt_ia, input_atom, nA / 64);
    bstat_k<160,64,0><<<dim3(256), dim3(256), 0, stream>>>(
        fb_bf, Wt_ib, input_bond, nB / 64);

    // message steps: MW = msg @ W_h[d]; msg' = relu(bond_in + bucket-sum - rev)
    const int combGrid = (nB * 40 + 255) / 256;
    const unsigned short* msg_cur = input_bond;
    for (int d = 0; d < 3; d++){
        bstat_k<320,32,1><<<dim3(256), dim3(256), 0, stream>>>(
            msg_cur, Wt_h + (size_t)d * 320 * 320, MW, nB / 32);
        comb_k<<<dim3(combGrid), dim3(256), 0, stream>>>(
            MW, input_bond, b_src, b2revb, cnt, bucket, msgA, nB);
        msg_cur = msgA;
    }

    // final per-atom aggregation (linear, no prod materialization)
    amsg_k<<<dim3((nA * 40 + 255) / 256), dim3(256), 0, stream>>>(
        msgA, cnt, bucket, amsg, nA);

    // atom_h = relu([input_atom | amsg | input_atom*amsg] @ W_o + b_o)
    // product fused in-kernel; three fenced 10-step sections (anti-spill)
    gemm_wo<<<dim3(nA / 32), dim3(256), 0, stream>>>(
        input_atom, amsg, Wt_o, b_o, atom_h, nA / 32);

    // per-molecule mean
    readout_k<<<dim3(nM), dim3(320), 0, stream>>>(atom_h, mol_ids, nA, (float*)d_out);
}

// Round 24
// 1948.802 us; speedup vs baseline: 1.3484x; 1.0057x over previous
//
#include <hip/hip_runtime.h>
#include <stdint.h>

#define H   300
#define HP  320
#define CAP 32     // max incoming bonds per atom (Binomial(400k,1/200k) max ~13)

using bf8 = __attribute__((ext_vector_type(8))) short;   // 8 x bf16
using s4  = __attribute__((ext_vector_type(4))) short;   // 4 x bf16 (8B store)
using f4  = __attribute__((ext_vector_type(4))) float;   // MFMA acc

__device__ __forceinline__ float bf2f(unsigned short u){
    union { unsigned int i; float f; } v; v.i = ((unsigned int)u) << 16; return v.f;
}
__device__ __forceinline__ unsigned short f2bf(float x){
    unsigned int u = __builtin_bit_cast(unsigned int, x);
    u = (u + 0x7FFFu + ((u >> 16) & 1u)) >> 16;   // RNE
    return (unsigned short)u;
}

// ---------------------------------------------------------------------------
// Incoming-bond bucket list: bucket[a][0..cnt[a]) = bond indices with dst==a
// ---------------------------------------------------------------------------
__global__ void fill_k(const int* __restrict__ b_dst, int* __restrict__ cnt,
                       int* __restrict__ bucket, int nB){
    int e = blockIdx.x * 256 + threadIdx.x;
    if (e >= nB) return;
    int d = b_dst[e];
    int slot = atomicAdd(&cnt[d], 1);
    if (slot < CAP) bucket[(long)d * CAP + slot] = e;
}

// ---------------------------------------------------------------------------
// Weight prep: W [Kact][H] fp32 -> Wt k-major [Ktot/32][320][32] bf16
// ---------------------------------------------------------------------------
__global__ void prep_wt(const float* __restrict__ W, unsigned short* __restrict__ Wt,
                        int Kact, int Kp){
    int idx = blockIdx.x * 256 + threadIdx.x;
    if (idx >= 320 * Kp) return;
    int t  = idx / (320 * 32);
    int r  = idx % (320 * 32);
    int n  = r / 32, kk = r % 32;
    int k  = t * 32 + kk;
    float v = (n < H && k < Kact) ? W[(long)k * H + n] : 0.f;
    Wt[idx] = f2bf(v);
}

// W_o [900][300] -> k-major [30][320][32]; k = t*32+kk, sec = k/320
__global__ void prep_wto(const float* __restrict__ W, unsigned short* __restrict__ Wt){
    int idx = blockIdx.x * 256 + threadIdx.x;
    if (idx >= 320 * 960) return;
    int t  = idx / (320 * 32);
    int r  = idx % (320 * 32);
    int n  = r / 32, kk = r % 32;
    int k  = t * 32 + kk;
    int sec = k / HP, ksec = k % HP;
    float v = (n < H && ksec < H) ? W[((long)sec * H + ksec) * H + n] : 0.f;
    Wt[idx] = f2bf(v);
}

// ---------------------------------------------------------------------------
// Input feature conversion: X fp32 [rows][Kact] -> Y bf16 [rows][160] linear
// ---------------------------------------------------------------------------
__global__ __launch_bounds__(256)
void conv_in(const float* __restrict__ X, int rows, int Kact,
             unsigned short* __restrict__ Y){
    int t = blockIdx.x * 256 + threadIdx.x;
    if (t >= rows * 20) return;
    int row = t / 20, c = t % 20;
    int k0 = c * 8;
    bf8 v;
    #pragma unroll
    for (int j = 0; j < 8; j++){
        int k = k0 + j;
        float f = (k < Kact) ? X[(long)row * Kact + k] : 0.f;
        v[j] = (short)f2bf(f);
    }
    *(bf8*)(Y + (long)row * 160 + k0) = v;
}

// ---------------------------------------------------------------------------
// B-stationary persistent GEMM:  out = epi( A[rows][RL] @ W^T ), BN-half=160
// grid = 256 (1 block/CU). Block owns N-half; B-half (RL x 160, k-major)
// lives in LDS for the whole kernel -> K-loop has ZERO global loads.
// A tiles REG-STAGED, DEEP-prefetched: loadSt(t+2) issued right after
// writeSt(t+1) -> the load is in flight across epilogue + barrier + the
// ENTIRE next K-loop (~1500-2000cy) before its writeSt consumes it.
// (256,1) -> 512-reg cap, st[5] live across K-loop is safe.
// LDS A image XOR-SWIZZLED (c ^= row&XM). EPI: 0 = relu, 1 = raw.
// ---------------------------------------------------------------------------
template<int RL, int BM, int EPI>
__global__ __launch_bounds__(256, 1)
void bstat_k(const unsigned short* __restrict__ A,    // linear [rows][RL]
             const unsigned short* __restrict__ Wt,   // k-major [T][320][32]
             unsigned short* __restrict__ outb,       // linear [rows][320]
             int nTiles)
{
    constexpr int T      = RL / 32;        // K-steps (5 or 10)
    constexpr int MF     = BM / 32;        // M frags per wave (1 or 2)
    constexpr int TILEB  = BM * RL * 2;    // 20480 both configs
    constexpr int CHUNKS = RL / 8;         // 16B chunks per row (40 or 20)
    constexpr int XM     = (CHUNKS % 8 == 0) ? 7 : 3;   // in-row XOR mask

    __shared__ char ldsB[T * 10240];       // [T][4][160][16B] : 50/100 KB
    __shared__ char ldsA[2][TILEB];        // 2 x 20KB, swizzled rows

    const int tid  = threadIdx.x;
    const int w    = tid >> 6;
    const int wm   = w >> 1, wn = w & 1;   // 2M x 2N wave grid
    const int lane = tid & 63;
    const int lr   = lane & 15;
    const int g    = lane >> 4;
    const int nh   = blockIdx.x & 1;       // N-half

    // ---- B half -> LDS, once. layout [t][g][n][16B] ----
    for (int idx = tid; idx < T * 640; idx += 256){
        int t  = idx / 640;
        int r  = idx - t * 640;
        int gg = r / 160;
        int n  = r - gg * 160;
        bf8 v = *(const bf8*)(Wt + ((long)t * 320 + nh * 160 + n) * 32 + gg * 8);
        *(bf8*)(ldsB + (long)idx * 16) = v;
    }

    bf8 st[5];                             // staging regs (live across K-loop;
                                           // (256,1) -> no cap -> no spill)
    auto loadSt = [&](int t){
        const char* g0 = (const char*)A + (long)t * TILEB + tid * 16;
        #pragma unroll
        for (int rd = 0; rd < 5; rd++)
            st[rd] = *(const bf8*)(g0 + rd * 4096);
    };
    auto writeSt = [&](int buf){
        #pragma unroll
        for (int rd = 0; rd < 5; rd++){
            int f = rd * 256 + tid;
            int row = f / CHUNKS, c = f % CHUNKS;
            *(bf8*)(ldsA[buf] + row * (RL * 2) + ((c ^ (row & XM)) << 4)) = st[rd];
        }
    };

    int tile = blockIdx.x >> 1;
    if (tile >= nTiles) return;
    loadSt(tile);
    writeSt(0);
    if (tile + 128 < nTiles) loadSt(tile + 128);   // deep prefetch: next tile
    __syncthreads();                        // B + first A tile visible

    int buf = 0;
    for (; tile < nTiles; tile += 128){
        int nt  = tile + 128;
        int nnt = tile + 256;

        f4 acc[MF][5];
        #pragma unroll
        for (int mf = 0; mf < MF; mf++)
            #pragma unroll
            for (int nf = 0; nf < 5; nf++)
                acc[mf][nf] = (f4){0.f, 0.f, 0.f, 0.f};

        #pragma unroll
        for (int t = 0; t < T; t++){
            bf8 bfr[5], af[MF];
            const char* bb = ldsB + (((t * 4 + g) * 160) + wn * 80 + lr) * 16;
            #pragma unroll
            for (int nf = 0; nf < 5; nf++)
                bfr[nf] = *(const bf8*)(bb + nf * 256);
            #pragma unroll
            for (int mf = 0; mf < MF; mf++){
                int row = wm * (BM / 2) + mf * 16 + lr;
                int ch  = t * 4 + g;
                af[mf] = *(const bf8*)(ldsA[buf] + row * (RL * 2)
                                       + ((ch ^ (row & XM)) << 4));
            }
            #pragma unroll
            for (int mf = 0; mf < MF; mf++)
                #pragma unroll
                for (int nf = 0; nf < 5; nf++)
                    acc[mf][nf] = __builtin_amdgcn_mfma_f32_16x16x32_bf16(
                        bfr[nf], af[mf], acc[mf][nf], 0, 0, 0);
        }

        // st holds nt's data (loaded a FULL iteration ago -> latency covered)
        if (nt < nTiles)  writeSt(buf ^ 1);
        if (nnt < nTiles) loadSt(nnt);      // in flight across epilogue +
                                            // barrier + next K-loop

        // epilogue: D^T -> lane holds row, 4 consecutive cols
        #pragma unroll
        for (int mf = 0; mf < MF; mf++){
            const long row = (long)tile * BM + wm * (BM / 2) + mf * 16 + lr;
            #pragma unroll
            for (int nf = 0; nf < 5; nf++){
                const int colg = nh * 160 + wn * 80 + nf * 16 + g * 4;
                s4 v4;
                #pragma unroll
                for (int q = 0; q < 4; q++){
                    float v = acc[mf][nf][q];
                    if constexpr (EPI == 0) v = fmaxf(v, 0.f);
                    v4[q] = (short)f2bf(v);
                }
                *(s4*)(outb + row * HP + colg) = v4;
            }
        }
        __syncthreads();                    // next tile's LDS image ready
        buf ^= 1;
    }
}

// ---------------------------------------------------------------------------
// Wo GEMM, fused product, SECTION-FENCED (anti-spill, r19-proven):
//   atom_h = relu(input_atom@W0 + amsg@W1 + (input_atom*amsg)@W2 + b_o)
// ---------------------------------------------------------------------------
__global__ __launch_bounds__(256, 4)
void gemm_wo(const unsigned short* __restrict__ A0,   // input_atom [rows][320]
             const unsigned short* __restrict__ A1,   // amsg       [rows][320]
             const unsigned short* __restrict__ Wt,   // k-major [30][320][32]
             const float* __restrict__ b_o,
             unsigned short* __restrict__ outb,       // linear [rows][320]
             int nTiles)
{
    __shared__ char lds0[32 * 640];        // XOR-swizzled
    __shared__ char lds1[32 * 640];

    const int tid  = threadIdx.x;
    const int w    = tid >> 6;             // N stripe of 80
    const int lane = tid & 63;
    const int lr   = lane & 15;
    const int g    = lane >> 4;

    int tile = blockIdx.x;
    if (tile >= nTiles) return;
    const long rowBase = (long)tile * 32;

    auto stageA = [&](const unsigned short* src, char* dst){
        const char* gb = (const char*)(src + rowBase * HP);
        bf8 st[5];                          // transient: dead before K-loop
        #pragma unroll
        for (int i = 0; i < 5; i++)
            st[i] = *(const bf8*)(gb + (i * 256 + tid) * 16);
        #pragma unroll
        for (int i = 0; i < 5; i++){
            int f = i * 256 + tid;
            int row = f / 40, c = f % 40;
            *(bf8*)(dst + row * 640 + ((c ^ (row & 7)) << 4)) = st[i];
        }
    };

    bf8 bb[2][5];
    auto loadB = [&](int t, bf8 (&dst)[5]){
        const unsigned short* base = Wt + ((long)t * 320) * 32 + g * 8;
        #pragma unroll
        for (int n = 0; n < 5; n++)
            dst[n] = *(const bf8*)(base + (w * 80 + n * 16 + lr) * 32);
    };

    stageA(A0, lds0);
    stageA(A1, lds1);
    loadB(0, bb[0]);                        // latency hides under stage drain
    __syncthreads();                        // LDS read-only after this

    f4 acc[2][5];
    #pragma unroll
    for (int m = 0; m < 2; m++)
        #pragma unroll
        for (int n = 0; n < 5; n++)
            acc[m][n] = (f4){0.f, 0.f, 0.f, 0.f};

    #pragma unroll
    for (int sec = 0; sec < 3; ++sec){
        if (sec > 0){
            __syncthreads();               // scheduling fence (anti-spill)
            loadB(sec * 10, bb[0]);
        }
        loadB(sec * 10 + 1, bb[1]);

        #pragma unroll
        for (int i = 0; i < 10; i++){
            bf8 af[2];
            #pragma unroll
            for (int m = 0; m < 2; m++){
                const int row = m * 16 + lr;
                const int off = row * 640 + (((i * 4 + g) ^ (row & 7)) << 4);
                if (sec == 0){
                    af[m] = *(const bf8*)(lds0 + off);
                } else if (sec == 1){
                    af[m] = *(const bf8*)(lds1 + off);
                } else {
                    bf8 a = *(const bf8*)(lds0 + off);
                    bf8 b = *(const bf8*)(lds1 + off);
                    #pragma unroll
                    for (int q = 0; q < 8; q++)
                        af[m][q] = (short)f2bf(bf2f((unsigned short)a[q]) *
                                               bf2f((unsigned short)b[q]));
                }
            }
            #pragma unroll
            for (int m = 0; m < 2; m++)
                #pragma unroll
                for (int n = 0; n < 5; n++)
                    acc[m][n] = __builtin_amdgcn_mfma_f32_16x16x32_bf16(
                        bb[i & 1][n], af[m], acc[m][n], 0, 0, 0);
            if (i + 2 < 10) loadB(sec * 10 + i + 2, bb[i & 1]);
        }
    }

    // epilogue: D^T -> lane holds row, 4 consecutive cols; + b_o, relu
    #pragma unroll
    for (int m = 0; m < 2; m++){
        const long row = rowBase + m * 16 + lr;
        #pragma unroll
        for (int n = 0; n < 5; n++){
            const int colg = w * 80 + n * 16 + g * 4;
            s4 v4;
            #pragma unroll
            for (int q = 0; q < 4; q++){
                int col = colg + q;
                float v = acc[m][n][q];
                v += (col < H ? b_o[col] : 0.f);
                v4[q] = (short)f2bf(fmaxf(v, 0.f));
            }
            *(s4*)(outb + row * HP + colg) = v4;
        }
    }
}

// ---------------------------------------------------------------------------
// comb: msg'[e] = relu(bond_in[e] + sum_{j in bucket[src[e]]} MW[j] - MW[rev[e]])
// thread = (bond, 16B chunk); 6 independent loads in flight. Linear layout.
// ---------------------------------------------------------------------------
__global__ __launch_bounds__(256)
void comb_k(const unsigned short* __restrict__ MW,
            const unsigned short* __restrict__ bond_in,
            const int* __restrict__ b_src, const int* __restrict__ b2revb,
            const int* __restrict__ cnt, const int* __restrict__ bucket,
            unsigned short* __restrict__ out, int nB){
    int t = blockIdx.x * 256 + threadIdx.x;
    if (t >= nB * 40) return;
    int e = t / 40, ch = t % 40;
    int k0 = ch * 8;
    int s   = b_src[e];
    int rev = b2revb[e];
    int dg = cnt[s]; if (dg > CAP) dg = CAP;
    long base = (long)s * CAP;
    int be0 = 0, be1 = 0, be2 = 0, be3 = 0;
    if (dg > 0) be0 = bucket[base + 0];
    if (dg > 1) be1 = bucket[base + 1];
    if (dg > 2) be2 = bucket[base + 2];
    if (dg > 3) be3 = bucket[base + 3];
    bf8 bi = *(const bf8*)(bond_in + (long)e * HP + k0);
    bf8 rv = *(const bf8*)(MW + (long)rev * HP + k0);
    bf8 m0, m1, m2, m3;
    if (dg > 0) m0 = *(const bf8*)(MW + (long)be0 * HP + k0);
    if (dg > 1) m1 = *(const bf8*)(MW + (long)be1 * HP + k0);
    if (dg > 2) m2 = *(const bf8*)(MW + (long)be2 * HP + k0);
    if (dg > 3) m3 = *(const bf8*)(MW + (long)be3 * HP + k0);
    float sacc[8];
    #pragma unroll
    for (int q = 0; q < 8; q++)
        sacc[q] = bf2f((unsigned short)bi[q]) - bf2f((unsigned short)rv[q]);
    auto addv = [&](bf8 mm){
        #pragma unroll
        for (int q = 0; q < 8; q++) sacc[q] += bf2f((unsigned short)mm[q]);
    };
    if (dg > 0) addv(m0);
    if (dg > 1) addv(m1);
    if (dg > 2) addv(m2);
    if (dg > 3) addv(m3);
    for (int j = 4; j < dg; ++j){
        int be = bucket[base + j];
        addv(*(const bf8*)(MW + (long)be * HP + k0));
    }
    bf8 v;
    #pragma unroll
    for (int q = 0; q < 8; q++) v[q] = (short)f2bf(fmaxf(sacc[q], 0.f));
    *(bf8*)(out + (long)e * HP + k0) = v;
}

// ---------------------------------------------------------------------------
// a_msg[a] = sum of msg rows with dst==a (bf16, linear)
// ---------------------------------------------------------------------------
__global__ __launch_bounds__(256)
void amsg_k(const unsigned short* __restrict__ msg, const int* __restrict__ cnt,
            const int* __restrict__ bucket,
            unsigned short* __restrict__ amsg, int nA){
    int t = blockIdx.x * 256 + threadIdx.x;
    if (t >= nA * 40) return;
    int a = t / 40, ch = t % 40;
    int k0 = ch * 8;
    int dg = cnt[a]; if (dg > CAP) dg = CAP;
    long base = (long)a * CAP;
    int be0 = 0, be1 = 0, be2 = 0, be3 = 0;
    if (dg > 0) be0 = bucket[base + 0];
    if (dg > 1) be1 = bucket[base + 1];
    if (dg > 2) be2 = bucket[base + 2];
    if (dg > 3) be3 = bucket[base + 3];
    bf8 m0, m1, m2, m3;
    if (dg > 0) m0 = *(const bf8*)(msg + (long)be0 * HP + k0);
    if (dg > 1) m1 = *(const bf8*)(msg + (long)be1 * HP + k0);
    if (dg > 2) m2 = *(const bf8*)(msg + (long)be2 * HP + k0);
    if (dg > 3) m3 = *(const bf8*)(msg + (long)be3 * HP + k0);
    float s[8];
    #pragma unroll
    for (int q = 0; q < 8; q++) s[q] = 0.f;
    auto addv = [&](bf8 mm){
        #pragma unroll
        for (int q = 0; q < 8; q++) s[q] += bf2f((unsigned short)mm[q]);
    };
    if (dg > 0) addv(m0);
    if (dg > 1) addv(m1);
    if (dg > 2) addv(m2);
    if (dg > 3) addv(m3);
    for (int j = 4; j < dg; ++j)
        addv(*(const bf8*)(msg + (long)bucket[base + j] * HP + k0));
    bf8 va;
    #pragma unroll
    for (int q = 0; q < 8; q++) va[q] = (short)f2bf(s[q]);
    *(bf8*)(amsg + (long)a * HP + k0) = va;
}

// ---------------------------------------------------------------------------
// Readout: per-molecule mean over sorted mol_ids (binary-search range)
// ---------------------------------------------------------------------------
__global__ __launch_bounds__(320)
void readout_k(const unsigned short* __restrict__ atom_h,
               const int* __restrict__ mol_ids, int nAtoms,
               float* __restrict__ out){
    int m = blockIdx.x;
    int t = threadIdx.x;
    int lo = 0, hi = nAtoms;
    while (lo < hi){ int mid = (lo + hi) >> 1; if (mol_ids[mid] < m) lo = mid + 1; else hi = mid; }
    int lo2 = lo, hi2 = nAtoms;
    while (lo2 < hi2){ int mid = (lo2 + hi2) >> 1; if (mol_ids[mid] < m + 1) lo2 = mid + 1; else hi2 = mid; }
    if (t < H){
        float s = 0.f;
        for (int a = lo; a < lo2; ++a) s += bf2f(atom_h[(long)a * HP + t]);
        int c2 = lo2 - lo;
        out[(long)m * H + t] = s / (float)(c2 > 0 ? c2 : 1);
    }
}

// ---------------------------------------------------------------------------
extern "C" void kernel_launch(void* const* d_in, const int* in_sizes, int n_in,
                              void* d_out, int out_size, void* d_ws, size_t ws_size,
                              hipStream_t stream){
    const float* f_atoms  = (const float*)d_in[0];
    const float* f_bonds  = (const float*)d_in[1];
    const float* W_i_atom = (const float*)d_in[2];
    const float* W_i_bond = (const float*)d_in[3];
    const float* W_h      = (const float*)d_in[4];
    const float* W_o      = (const float*)d_in[5];
    const float* b_o      = (const float*)d_in[6];
    const int* b_src   = (const int*)d_in[7];
    const int* b_dst   = (const int*)d_in[8];
    const int* b2revb  = (const int*)d_in[9];
    const int* mol_ids = (const int*)d_in[10];

    const int nA = in_sizes[10];          // 200000
    const int nB = in_sizes[7];           // 400000
    const int nM = out_size / H;          // 4096

    char* p = (char*)d_ws;
    auto alloc = [&](size_t bytes){ char* q = p; p += (bytes + 255) & ~(size_t)255; return q; };
    unsigned short* Wt_ia = (unsigned short*)alloc((size_t)320 * 160 * 2);
    unsigned short* Wt_ib = (unsigned short*)alloc((size_t)320 * 160 * 2);
    unsigned short* Wt_h  = (unsigned short*)alloc((size_t)3 * 320 * 320 * 2);
    unsigned short* Wt_o  = (unsigned short*)alloc((size_t)320 * 960 * 2);
    int* cnt    = (int*)alloc((size_t)nA * 4);
    int* bucket = (int*)alloc((size_t)nA * CAP * 4);
    unsigned short* input_atom = (unsigned short*)alloc((size_t)nA * HP * 2);
    unsigned short* input_bond = (unsigned short*)alloc((size_t)nB * HP * 2);
    unsigned short* msgA = (unsigned short*)alloc((size_t)nB * HP * 2);
    unsigned short* MW   = (unsigned short*)alloc((size_t)nB * HP * 2);
    // aliases into dead regions:
    unsigned short* fa_bf  = MW;                                  // [nA][160]
    unsigned short* fb_bf  = MW + (size_t)nA * 160;               // [nB][160]
    unsigned short* amsg   = MW;                                  // MW dead after comb3
    unsigned short* atom_h = input_bond;                          // dead after comb3

    if ((size_t)(p - (char*)d_ws) > ws_size) return;  // diagnostic: ws too small

    // adjacency buckets
    hipMemsetAsync(cnt, 0, (size_t)nA * 4, stream);
    fill_k<<<dim3((nB + 255) / 256), dim3(256), 0, stream>>>(b_dst, cnt, bucket, nB);

    // weight prep (k-major) + input conversion (linear)
    prep_wt<<<dim3((320*160 + 255)/256), dim3(256), 0, stream>>>(W_i_atom, Wt_ia, 133, 160);
    prep_wt<<<dim3((320*160 + 255)/256), dim3(256), 0, stream>>>(W_i_bond, Wt_ib, 147, 160);
    for (int d = 0; d < 3; d++)
        prep_wt<<<dim3((320*320 + 255)/256), dim3(256), 0, stream>>>(
            W_h + (size_t)d * H * H, Wt_h + (size_t)d * 320 * 320, 300, 320);
    prep_wto<<<dim3((320*960 + 255)/256), dim3(256), 0, stream>>>(W_o, Wt_o);
    conv_in<<<dim3((nA*20 + 255)/256), dim3(256), 0, stream>>>(f_atoms, nA, 133, fa_bf);
    conv_in<<<dim3((nB*20 + 255)/256), dim3(256), 0, stream>>>(f_bonds, nB, 147, fb_bf);

    // input projections (B-stationary, RL=160, BM=64)
    bstat_k<160,64,0><<<dim3(256), dim3(256), 0, stream>>>(
        fa_bf, Wt_ia, input_atom, nA / 64);
    bstat_k<160,64,0><<<dim3(256), dim3(256), 0, stream>>>(
        fb_bf, Wt_ib, input_bond, nB / 64);

    // message steps: MW = msg @ W_h[d]; msg' = relu(bond_in + bucket-sum - rev)
    const int combGrid = (nB * 40 + 255) / 256;
    const unsigned short* msg_cur = input_bond;
    for (int d = 0; d < 3; d++){
        bstat_k<320,32,1><<<dim3(256), dim3(256), 0, stream>>>(
            msg_cur, Wt_h + (size_t)d * 320 * 320, MW, nB / 32);
        comb_k<<<dim3(combGrid), dim3(256), 0, stream>>>(
            MW, input_bond, b_src, b2revb, cnt, bucket, msgA, nB);
        msg_cur = msgA;
    }

    // final per-atom aggregation (linear, no prod materialization)
    amsg_k<<<dim3((nA * 40 + 255) / 256), dim3(256), 0, stream>>>(
        msgA, cnt, bucket, amsg, nA);

    // atom_h = relu([input_atom | amsg | input_atom*amsg] @ W_o + b_o)
    // product fused in-kernel; three fenced 10-step sections (anti-spill)
    gemm_wo<<<dim3(nA / 32), dim3(256), 0, stream>>>(
        input_atom, amsg, Wt_o, b_o, atom_h, nA / 32);

    // per-molecule mean
    readout_k<<<dim3(nM), dim3(320), 0, stream>>>(atom_h, mol_ids, nA, (float*)d_out);
}